// Round 1
// baseline (1996.383 us; speedup 1.0000x reference)
//
#include <hip/hip_runtime.h>
#include <math.h>

#define NB 4
#define NT 2048
#define NE 1024
#define NH 16
#define ND 64
#define NF 32

// ============================================================================
// Kernel 1: QKV projection (C = X * W^T + bias) with fused rotary epilogue.
// X: [8192,1024] f32, W: [3072,1024] f32 (row-major, NT layout -> W rows
// contiguous in k). Output Q,K,V each in (B,H,T,D) f32.
// Tile: BM=BN=128, BK=16, 256 threads, 8x8 micro-tile per thread (split 4+4
// with +64 offset so LDS reads are <=2-way bank aliased).
// ============================================================================
__global__ __launch_bounds__(256)
void qkv_rotary_kernel(const float* __restrict__ X,
                       const float* __restrict__ W,
                       const float* __restrict__ bias,
                       const float* __restrict__ pos,
                       const float* __restrict__ freqs,
                       float* __restrict__ Qb,
                       float* __restrict__ Kb,
                       float* __restrict__ Vb)
{
    __shared__ float As[16][132];   // [k][m], padded
    __shared__ float Bs[16][132];   // [k][n], padded

    const int tid = threadIdx.x;
    const int m0 = blockIdx.x * 128;
    const int n0 = blockIdx.y * 128;
    const int ry = tid >> 4;        // 0..15
    const int tx = tid & 15;        // 0..15
    const int lr  = tid >> 2;       // 0..63 (staging row)
    const int lc4 = (tid & 3) * 4;  // 0,4,8,12 (staging col)

    float acc[8][8];
    #pragma unroll
    for (int i = 0; i < 8; ++i)
        #pragma unroll
        for (int j = 0; j < 8; ++j) acc[i][j] = 0.0f;

    for (int kt = 0; kt < NE; kt += 16) {
        float4 a0 = *(const float4*)(X + (size_t)(m0 + lr) * NE + kt + lc4);
        float4 a1 = *(const float4*)(X + (size_t)(m0 + 64 + lr) * NE + kt + lc4);
        float4 b0 = *(const float4*)(W + (size_t)(n0 + lr) * NE + kt + lc4);
        float4 b1 = *(const float4*)(W + (size_t)(n0 + 64 + lr) * NE + kt + lc4);
        As[lc4+0][lr]    = a0.x; As[lc4+1][lr]    = a0.y; As[lc4+2][lr]    = a0.z; As[lc4+3][lr]    = a0.w;
        As[lc4+0][64+lr] = a1.x; As[lc4+1][64+lr] = a1.y; As[lc4+2][64+lr] = a1.z; As[lc4+3][64+lr] = a1.w;
        Bs[lc4+0][lr]    = b0.x; Bs[lc4+1][lr]    = b0.y; Bs[lc4+2][lr]    = b0.z; Bs[lc4+3][lr]    = b0.w;
        Bs[lc4+0][64+lr] = b1.x; Bs[lc4+1][64+lr] = b1.y; Bs[lc4+2][64+lr] = b1.z; Bs[lc4+3][64+lr] = b1.w;
        __syncthreads();
        #pragma unroll
        for (int k = 0; k < 16; ++k) {
            float av[8], bv[8];
            *(float4*)&av[0] = *(const float4*)&As[k][ry*4];
            *(float4*)&av[4] = *(const float4*)&As[k][64 + ry*4];
            *(float4*)&bv[0] = *(const float4*)&Bs[k][tx*4];
            *(float4*)&bv[4] = *(const float4*)&Bs[k][64 + tx*4];
            #pragma unroll
            for (int i = 0; i < 8; ++i)
                #pragma unroll
                for (int j = 0; j < 8; ++j)
                    acc[i][j] = fmaf(av[i], bv[j], acc[i][j]);
        }
        __syncthreads();
    }

    // Epilogue: bias + (rotary for q,k) + scatter into (B,H,T,D)
    const int sec = n0 >> 10;       // 0:q 1:k 2:v  (128-col block never spans)
    const int e0  = n0 & 1023;
    float* dst = (sec == 0) ? Qb : (sec == 1) ? Kb : Vb;

    #pragma unroll
    for (int i = 0; i < 8; ++i) {
        const int rr = (i < 4) ? (ry*4 + i) : (64 + ry*4 + (i - 4));
        const int m  = m0 + rr;
        const int b  = m >> 11;     // /T
        const int t  = m & 2047;    // %T
        if (sec == 2) {
            #pragma unroll
            for (int j = 0; j < 8; ++j) {
                const int cc = (j < 4) ? (tx*4 + j) : (64 + tx*4 + (j - 4));
                const int e  = e0 + cc;
                const int h  = e >> 6, d = e & 63;
                dst[((size_t)(b*NH + h)*NT + t)*ND + d] = acc[i][j] + bias[n0 + cc];
            }
        } else {
            const float px = pos[(size_t)m*3 + 0];
            const float py = pos[(size_t)m*3 + 1];
            const float pz = pos[(size_t)m*3 + 2];
            #pragma unroll
            for (int jp = 0; jp < 4; ++jp) {
                const int j0 = jp*2, j1 = j0 + 1;
                const int cc0 = (j0 < 4) ? (tx*4 + j0) : (64 + tx*4 + (j0 - 4));
                const int e   = e0 + cc0;
                const int h   = e >> 6, d0 = e & 63, f = d0 >> 1;
                const float* frq = freqs + ((size_t)h*NF + f)*3;
                const float ang = px*frq[0] + py*frq[1] + pz*frq[2];
                float sn, cs;
                sincosf(ang, &sn, &cs);
                const float x0 = acc[i][j0] + bias[n0 + cc0];
                const float x1 = acc[i][j1] + bias[n0 + cc0 + 1];
                const size_t base = ((size_t)(b*NH + h)*NT + t)*ND + d0;
                dst[base + 0] = x0*cs - x1*sn;
                dst[base + 1] = x0*sn + x1*cs;
            }
        }
    }
}

// ============================================================================
// Kernel 2: fp32 flash attention. One block = (b*H+h, 64 q-rows).
// BK=64. Online softmax state (m,l) lives in registers, replicated across the
// 16 lanes that own a q-row (shfl_xor reductions). P aliases KsT LDS buffer.
// ============================================================================
__global__ __launch_bounds__(256)
void attn_kernel(const float* __restrict__ Qg, const float* __restrict__ Kg,
                 const float* __restrict__ Vg, float* __restrict__ Og)
{
    __shared__ float Qs[64][68];    // [qrow][d], pre-scaled by 1/8
    __shared__ float KsT[64][68];   // [d][key]; reused as P[qrow][key]
    __shared__ float Vs[64][68];    // [key][d]
    float (* const Ps)[68] = KsT;

    const int tid = threadIdx.x;
    const int bh  = blockIdx.x;     // b*H + h
    const int qt  = blockIdx.y;
    const int b = bh >> 4, h = bh & 15;
    const float* Qp = Qg + (size_t)bh * NT * ND;
    const float* Kp = Kg + (size_t)bh * NT * ND;
    const float* Vp = Vg + (size_t)bh * NT * ND;
    const int ry = tid >> 4, tx = tid & 15;

    {   // load Q tile once, scaled
        const int r  = tid >> 2;
        const int cb = (tid & 3) * 16;
        #pragma unroll
        for (int u = 0; u < 4; ++u) {
            float4 q = *(const float4*)(Qp + (size_t)(qt*64 + r)*ND + cb + u*4);
            q.x *= 0.125f; q.y *= 0.125f; q.z *= 0.125f; q.w *= 0.125f;
            *(float4*)&Qs[r][cb + u*4] = q;
        }
    }

    float m_i[4], l_i[4], o[4][4];
    #pragma unroll
    for (int i = 0; i < 4; ++i) {
        m_i[i] = -INFINITY; l_i[i] = 0.0f;
        #pragma unroll
        for (int j = 0; j < 4; ++j) o[i][j] = 0.0f;
    }

    for (int kt = 0; kt < NT; kt += 64) {
        {   // stage K transposed + V natural
            const int r  = tid >> 2;
            const int cb = (tid & 3) * 16;
            #pragma unroll
            for (int u = 0; u < 4; ++u) {
                const int c = cb + u*4;
                float4 kq = *(const float4*)(Kp + (size_t)(kt + r)*ND + c);
                KsT[c+0][r] = kq.x; KsT[c+1][r] = kq.y; KsT[c+2][r] = kq.z; KsT[c+3][r] = kq.w;
                float4 vq = *(const float4*)(Vp + (size_t)(kt + r)*ND + c);
                *(float4*)&Vs[r][c] = vq;
            }
        }
        __syncthreads();

        // S = Qs . K^T  (thread: rows ry*4.., cols tx*4..)
        float s[4][4];
        #pragma unroll
        for (int i = 0; i < 4; ++i)
            #pragma unroll
            for (int j = 0; j < 4; ++j) s[i][j] = 0.0f;

        #pragma unroll
        for (int d4 = 0; d4 < 64; d4 += 4) {
            float qv[4][4], kv[4][4];
            #pragma unroll
            for (int i = 0; i < 4; ++i)
                *(float4*)qv[i] = *(const float4*)&Qs[ry*4 + i][d4];
            #pragma unroll
            for (int dd = 0; dd < 4; ++dd)
                *(float4*)kv[dd] = *(const float4*)&KsT[d4 + dd][tx*4];
            #pragma unroll
            for (int i = 0; i < 4; ++i)
                #pragma unroll
                for (int dd = 0; dd < 4; ++dd)
                    #pragma unroll
                    for (int j = 0; j < 4; ++j)
                        s[i][j] = fmaf(qv[i][dd], kv[dd][j], s[i][j]);
        }
        __syncthreads();   // everyone done reading KsT before P overwrites it

        // online softmax (per-row state replicated over the row's 16 lanes)
        #pragma unroll
        for (int i = 0; i < 4; ++i) {
            float rm = fmaxf(fmaxf(s[i][0], s[i][1]), fmaxf(s[i][2], s[i][3]));
            rm = fmaxf(rm, __shfl_xor(rm, 1));
            rm = fmaxf(rm, __shfl_xor(rm, 2));
            rm = fmaxf(rm, __shfl_xor(rm, 4));
            rm = fmaxf(rm, __shfl_xor(rm, 8));
            const float mnew  = fmaxf(m_i[i], rm);
            const float alpha = __expf(m_i[i] - mnew);
            const float p0 = __expf(s[i][0] - mnew);
            const float p1 = __expf(s[i][1] - mnew);
            const float p2 = __expf(s[i][2] - mnew);
            const float p3 = __expf(s[i][3] - mnew);
            float rs = p0 + p1 + p2 + p3;
            rs += __shfl_xor(rs, 1);
            rs += __shfl_xor(rs, 2);
            rs += __shfl_xor(rs, 4);
            rs += __shfl_xor(rs, 8);
            l_i[i] = l_i[i]*alpha + rs;
            m_i[i] = mnew;
            #pragma unroll
            for (int j = 0; j < 4; ++j) o[i][j] *= alpha;
            float4 pv4 = make_float4(p0, p1, p2, p3);
            *(float4*)&Ps[ry*4 + i][tx*4] = pv4;
        }
        __syncthreads();

        // O += P . V  (thread: rows ry*4.., d-cols tx*4..)
        #pragma unroll
        for (int c4 = 0; c4 < 64; c4 += 4) {
            float pa[4][4], vb[4][4];
            #pragma unroll
            for (int i = 0; i < 4; ++i)
                *(float4*)pa[i] = *(const float4*)&Ps[ry*4 + i][c4];
            #pragma unroll
            for (int cc = 0; cc < 4; ++cc)
                *(float4*)vb[cc] = *(const float4*)&Vs[c4 + cc][tx*4];
            #pragma unroll
            for (int i = 0; i < 4; ++i)
                #pragma unroll
                for (int cc = 0; cc < 4; ++cc)
                    #pragma unroll
                    for (int j = 0; j < 4; ++j)
                        o[i][j] = fmaf(pa[i][cc], vb[cc][j], o[i][j]);
        }
        __syncthreads();
    }

    // write O in (B,T,E) layout: row qt*64+r, col h*64+d
    #pragma unroll
    for (int i = 0; i < 4; ++i) {
        const float inv = 1.0f / l_i[i];
        float4 ov = make_float4(o[i][0]*inv, o[i][1]*inv, o[i][2]*inv, o[i][3]*inv);
        *(float4*)(Og + ((size_t)b*NT + qt*64 + ry*4 + i)*NE + h*ND + tx*4) = ov;
    }
}

// ============================================================================
// Kernel 3: out-projection GEMM: out = O * Wo^T + bias. Same tile structure.
// ============================================================================
__global__ __launch_bounds__(256)
void out_proj_kernel(const float* __restrict__ A,   // [8192][1024]
                     const float* __restrict__ W,   // [1024][1024]
                     const float* __restrict__ bias,
                     float* __restrict__ out)
{
    __shared__ float As[16][132];
    __shared__ float Bs[16][132];

    const int tid = threadIdx.x;
    const int m0 = blockIdx.x * 128;
    const int n0 = blockIdx.y * 128;
    const int ry = tid >> 4;
    const int tx = tid & 15;
    const int lr  = tid >> 2;
    const int lc4 = (tid & 3) * 4;

    float acc[8][8];
    #pragma unroll
    for (int i = 0; i < 8; ++i)
        #pragma unroll
        for (int j = 0; j < 8; ++j) acc[i][j] = 0.0f;

    for (int kt = 0; kt < NE; kt += 16) {
        float4 a0 = *(const float4*)(A + (size_t)(m0 + lr) * NE + kt + lc4);
        float4 a1 = *(const float4*)(A + (size_t)(m0 + 64 + lr) * NE + kt + lc4);
        float4 b0 = *(const float4*)(W + (size_t)(n0 + lr) * NE + kt + lc4);
        float4 b1 = *(const float4*)(W + (size_t)(n0 + 64 + lr) * NE + kt + lc4);
        As[lc4+0][lr]    = a0.x; As[lc4+1][lr]    = a0.y; As[lc4+2][lr]    = a0.z; As[lc4+3][lr]    = a0.w;
        As[lc4+0][64+lr] = a1.x; As[lc4+1][64+lr] = a1.y; As[lc4+2][64+lr] = a1.z; As[lc4+3][64+lr] = a1.w;
        Bs[lc4+0][lr]    = b0.x; Bs[lc4+1][lr]    = b0.y; Bs[lc4+2][lr]    = b0.z; Bs[lc4+3][lr]    = b0.w;
        Bs[lc4+0][64+lr] = b1.x; Bs[lc4+1][64+lr] = b1.y; Bs[lc4+2][64+lr] = b1.z; Bs[lc4+3][64+lr] = b1.w;
        __syncthreads();
        #pragma unroll
        for (int k = 0; k < 16; ++k) {
            float av[8], bv[8];
            *(float4*)&av[0] = *(const float4*)&As[k][ry*4];
            *(float4*)&av[4] = *(const float4*)&As[k][64 + ry*4];
            *(float4*)&bv[0] = *(const float4*)&Bs[k][tx*4];
            *(float4*)&bv[4] = *(const float4*)&Bs[k][64 + tx*4];
            #pragma unroll
            for (int i = 0; i < 8; ++i)
                #pragma unroll
                for (int j = 0; j < 8; ++j)
                    acc[i][j] = fmaf(av[i], bv[j], acc[i][j]);
        }
        __syncthreads();
    }

    #pragma unroll
    for (int i = 0; i < 8; ++i) {
        const int rr = (i < 4) ? (ry*4 + i) : (64 + ry*4 + (i - 4));
        const int m  = m0 + rr;
        float4 c0, c1;
        c0.x = acc[i][0] + bias[n0 + tx*4 + 0];
        c0.y = acc[i][1] + bias[n0 + tx*4 + 1];
        c0.z = acc[i][2] + bias[n0 + tx*4 + 2];
        c0.w = acc[i][3] + bias[n0 + tx*4 + 3];
        c1.x = acc[i][4] + bias[n0 + 64 + tx*4 + 0];
        c1.y = acc[i][5] + bias[n0 + 64 + tx*4 + 1];
        c1.z = acc[i][6] + bias[n0 + 64 + tx*4 + 2];
        c1.w = acc[i][7] + bias[n0 + 64 + tx*4 + 3];
        *(float4*)(out + (size_t)m*NE + n0 + tx*4)      = c0;
        *(float4*)(out + (size_t)m*NE + n0 + 64 + tx*4) = c1;
    }
}

extern "C" void kernel_launch(void* const* d_in, const int* in_sizes, int n_in,
                              void* d_out, int out_size, void* d_ws, size_t ws_size,
                              hipStream_t stream)
{
    const float* X   = (const float*)d_in[0];   // query   [4,2048,1024]
    const float* pos = (const float*)d_in[1];   // positions [4,2048,3]
    const float* Wi  = (const float*)d_in[2];   // in_proj_weight [3072,1024]
    const float* bi  = (const float*)d_in[3];   // in_proj_bias [3072]
    const float* Wo  = (const float*)d_in[4];   // out_proj_weight [1024,1024]
    const float* bo  = (const float*)d_in[5];   // out_proj_bias [1024]
    const float* fr  = (const float*)d_in[6];   // freqs [16,32,3]
    float* out = (float*)d_out;

    const size_t SZ = (size_t)NB * NH * NT * ND;   // 8,388,608 floats
    float* Qb = (float*)d_ws;
    float* Kb = Qb + SZ;
    float* Vb = Kb + SZ;
    float* Ob = Vb + SZ;

    qkv_rotary_kernel<<<dim3(64, 24), 256, 0, stream>>>(X, Wi, bi, pos, fr, Qb, Kb, Vb);
    attn_kernel     <<<dim3(64, 32), 256, 0, stream>>>(Qb, Kb, Vb, Ob);
    out_proj_kernel <<<dim3(64, 8),  256, 0, stream>>>(Ob, Wo, bo, out);
}

// Round 2
// 1047.444 us; speedup vs baseline: 1.9060x; 1.9060x over previous
//
#include <hip/hip_runtime.h>
#include <math.h>

#define NB 4
#define NT 2048
#define NE 1024
#define NH 16
#define ND 64
#define NF 32

typedef _Float16 half8 __attribute__((ext_vector_type(8)));
typedef _Float16 half4 __attribute__((ext_vector_type(4)));
typedef float f32x4 __attribute__((ext_vector_type(4)));
#define MFMA16(a, b, c) __builtin_amdgcn_mfma_f32_16x16x32_f16(a, b, c, 0, 0, 0)

// ============================================================================
// Kernel 1: QKV projection (C = X * W^T + bias) with fused rotary epilogue.
// fp32 VALU GEMM (unchanged from R1).
// ============================================================================
__global__ __launch_bounds__(256)
void qkv_rotary_kernel(const float* __restrict__ X,
                       const float* __restrict__ W,
                       const float* __restrict__ bias,
                       const float* __restrict__ pos,
                       const float* __restrict__ freqs,
                       float* __restrict__ Qb,
                       float* __restrict__ Kb,
                       float* __restrict__ Vb)
{
    __shared__ float As[16][132];   // [k][m], padded
    __shared__ float Bs[16][132];   // [k][n], padded

    const int tid = threadIdx.x;
    const int m0 = blockIdx.x * 128;
    const int n0 = blockIdx.y * 128;
    const int ry = tid >> 4;        // 0..15
    const int tx = tid & 15;        // 0..15
    const int lr  = tid >> 2;       // 0..63 (staging row)
    const int lc4 = (tid & 3) * 4;  // 0,4,8,12 (staging col)

    float acc[8][8];
    #pragma unroll
    for (int i = 0; i < 8; ++i)
        #pragma unroll
        for (int j = 0; j < 8; ++j) acc[i][j] = 0.0f;

    for (int kt = 0; kt < NE; kt += 16) {
        float4 a0 = *(const float4*)(X + (size_t)(m0 + lr) * NE + kt + lc4);
        float4 a1 = *(const float4*)(X + (size_t)(m0 + 64 + lr) * NE + kt + lc4);
        float4 b0 = *(const float4*)(W + (size_t)(n0 + lr) * NE + kt + lc4);
        float4 b1 = *(const float4*)(W + (size_t)(n0 + 64 + lr) * NE + kt + lc4);
        As[lc4+0][lr]    = a0.x; As[lc4+1][lr]    = a0.y; As[lc4+2][lr]    = a0.z; As[lc4+3][lr]    = a0.w;
        As[lc4+0][64+lr] = a1.x; As[lc4+1][64+lr] = a1.y; As[lc4+2][64+lr] = a1.z; As[lc4+3][64+lr] = a1.w;
        Bs[lc4+0][lr]    = b0.x; Bs[lc4+1][lr]    = b0.y; Bs[lc4+2][lr]    = b0.z; Bs[lc4+3][lr]    = b0.w;
        Bs[lc4+0][64+lr] = b1.x; Bs[lc4+1][64+lr] = b1.y; Bs[lc4+2][64+lr] = b1.z; Bs[lc4+3][64+lr] = b1.w;
        __syncthreads();
        #pragma unroll
        for (int k = 0; k < 16; ++k) {
            float av[8], bv[8];
            *(float4*)&av[0] = *(const float4*)&As[k][ry*4];
            *(float4*)&av[4] = *(const float4*)&As[k][64 + ry*4];
            *(float4*)&bv[0] = *(const float4*)&Bs[k][tx*4];
            *(float4*)&bv[4] = *(const float4*)&Bs[k][64 + tx*4];
            #pragma unroll
            for (int i = 0; i < 8; ++i)
                #pragma unroll
                for (int j = 0; j < 8; ++j)
                    acc[i][j] = fmaf(av[i], bv[j], acc[i][j]);
        }
        __syncthreads();
    }

    // Epilogue: bias + (rotary for q,k) + scatter into (B,H,T,D)
    const int sec = n0 >> 10;       // 0:q 1:k 2:v  (128-col block never spans)
    const int e0  = n0 & 1023;
    float* dst = (sec == 0) ? Qb : (sec == 1) ? Kb : Vb;

    #pragma unroll
    for (int i = 0; i < 8; ++i) {
        const int rr = (i < 4) ? (ry*4 + i) : (64 + ry*4 + (i - 4));
        const int m  = m0 + rr;
        const int b  = m >> 11;     // /T
        const int t  = m & 2047;    // %T
        if (sec == 2) {
            #pragma unroll
            for (int j = 0; j < 8; ++j) {
                const int cc = (j < 4) ? (tx*4 + j) : (64 + tx*4 + (j - 4));
                const int e  = e0 + cc;
                const int h  = e >> 6, d = e & 63;
                dst[((size_t)(b*NH + h)*NT + t)*ND + d] = acc[i][j] + bias[n0 + cc];
            }
        } else {
            const float px = pos[(size_t)m*3 + 0];
            const float py = pos[(size_t)m*3 + 1];
            const float pz = pos[(size_t)m*3 + 2];
            #pragma unroll
            for (int jp = 0; jp < 4; ++jp) {
                const int j0 = jp*2, j1 = j0 + 1;
                const int cc0 = (j0 < 4) ? (tx*4 + j0) : (64 + tx*4 + (j0 - 4));
                const int e   = e0 + cc0;
                const int h   = e >> 6, d0 = e & 63, f = d0 >> 1;
                const float* frq = freqs + ((size_t)h*NF + f)*3;
                const float ang = px*frq[0] + py*frq[1] + pz*frq[2];
                float sn, cs;
                sincosf(ang, &sn, &cs);
                const float x0 = acc[i][j0] + bias[n0 + cc0];
                const float x1 = acc[i][j1] + bias[n0 + cc0 + 1];
                const size_t base = ((size_t)(b*NH + h)*NT + t)*ND + d0;
                dst[base + 0] = x0*cs - x1*sn;
                dst[base + 1] = x0*sn + x1*cs;
            }
        }
    }
}

// ============================================================================
// Kernel 2: fp16-MFMA flash attention.
// Block = 256 threads (4 waves). Each wave owns 32 q-rows; block covers 128.
// Swapped QK^T: S^T = mfma(A=K, B=Q^T) so key-reduce is 2 shfl_xor (16,32).
// KV tile = 64, K staged [key][d] fp16 (A-frags), V staged transposed [d][key]
// fp16 (B-frags), both with 72-elem rows (144B stride -> 2-way-free b128).
// P re-laid-out into A-frags via a per-wave LDS buffer (packed half4 writes).
// alpha/l redistributed softmax-layout -> O-frag-layout via 8 shfl.
// ============================================================================
__global__ __launch_bounds__(256)
void attn_mfma_kernel(const float* __restrict__ Qg, const float* __restrict__ Kg,
                      const float* __restrict__ Vg, float* __restrict__ Og)
{
    __shared__ _Float16 Ks[64][72];      // [key][d]
    __shared__ _Float16 VsT[64][72];     // [d][key]
    __shared__ _Float16 Pl[4][32][72];   // per-wave [q][key]

    const int tid  = threadIdx.x;
    const int wid  = tid >> 6;
    const int lane = tid & 63;
    const int ln   = lane & 15;
    const int g    = lane >> 4;
    const int bh   = blockIdx.x;
    const int qt   = blockIdx.y;
    const int b = bh >> 4, h = bh & 15;
    const float* Qp = Qg + (size_t)bh * NT * ND;
    const float* Kp = Kg + (size_t)bh * NT * ND;
    const float* Vp = Vg + (size_t)bh * NT * ND;

    const int qbase = qt*128 + wid*32;

    // Q fragments (B-operand: B[k=d][col=q]), scaled by 1/8, fp16, in regs
    half8 qfr[2][2];
    #pragma unroll
    for (int qf = 0; qf < 2; ++qf)
        #pragma unroll
        for (int ks = 0; ks < 2; ++ks) {
            const float* src = Qp + (size_t)(qbase + 16*qf + ln)*ND + 32*ks + 8*g;
            float4 qa = *(const float4*)(src);
            float4 qb = *(const float4*)(src + 4);
            half8 v;
            v[0]=(_Float16)(qa.x*0.125f); v[1]=(_Float16)(qa.y*0.125f);
            v[2]=(_Float16)(qa.z*0.125f); v[3]=(_Float16)(qa.w*0.125f);
            v[4]=(_Float16)(qb.x*0.125f); v[5]=(_Float16)(qb.y*0.125f);
            v[6]=(_Float16)(qb.z*0.125f); v[7]=(_Float16)(qb.w*0.125f);
            qfr[qf][ks] = v;
        }

    f32x4 o[2][4];
    float m_i[2], l_i[2];
    #pragma unroll
    for (int qf = 0; qf < 2; ++qf) {
        m_i[qf] = -INFINITY; l_i[qf] = 0.0f;
        #pragma unroll
        for (int nf = 0; nf < 4; ++nf) o[qf][nf] = (f32x4){0.f,0.f,0.f,0.f};
    }

    const int sr  = tid >> 2;         // 0..63 staging row (key)
    const int sc0 = (tid & 3) * 16;   // staging col base

    for (int kt = 0; kt < NT; kt += 64) {
        // ---- stage K (row-major fp16) + V (transposed fp16) ----
        #pragma unroll
        for (int u = 0; u < 4; ++u) {
            const int c = sc0 + u*4;
            float4 kq = *(const float4*)(Kp + (size_t)(kt + sr)*ND + c);
            half4 kh; kh[0]=(_Float16)kq.x; kh[1]=(_Float16)kq.y;
                      kh[2]=(_Float16)kq.z; kh[3]=(_Float16)kq.w;
            *(half4*)&Ks[sr][c] = kh;
            float4 vq = *(const float4*)(Vp + (size_t)(kt + sr)*ND + c);
            VsT[c+0][sr] = (_Float16)vq.x;
            VsT[c+1][sr] = (_Float16)vq.y;
            VsT[c+2][sr] = (_Float16)vq.z;
            VsT[c+3][sr] = (_Float16)vq.w;
        }
        __syncthreads();

        // ---- S^T = K . Q^T : frags st[mf(key)][qf(q)] ----
        f32x4 st[4][2];
        #pragma unroll
        for (int mf = 0; mf < 4; ++mf)
            #pragma unroll
            for (int qf = 0; qf < 2; ++qf) st[mf][qf] = (f32x4){0.f,0.f,0.f,0.f};

        #pragma unroll
        for (int ks = 0; ks < 2; ++ks) {
            half8 kf[4];
            #pragma unroll
            for (int mf = 0; mf < 4; ++mf)
                kf[mf] = *(const half8*)&Ks[16*mf + ln][8*g + 32*ks];
            #pragma unroll
            for (int mf = 0; mf < 4; ++mf)
                #pragma unroll
                for (int qf = 0; qf < 2; ++qf)
                    st[mf][qf] = MFMA16(kf[mf], qfr[qf][ks], st[mf][qf]);
        }

        // ---- online softmax (q = ln + 16*qf; lane holds keys 16mf+4g+r) ----
        float al[2];
        #pragma unroll
        for (int qf = 0; qf < 2; ++qf) {
            float rm = -INFINITY;
            #pragma unroll
            for (int mf = 0; mf < 4; ++mf)
                #pragma unroll
                for (int r = 0; r < 4; ++r) rm = fmaxf(rm, st[mf][qf][r]);
            rm = fmaxf(rm, __shfl_xor(rm, 16));
            rm = fmaxf(rm, __shfl_xor(rm, 32));
            const float mnew  = fmaxf(m_i[qf], rm);
            const float alpha = __expf(m_i[qf] - mnew);
            float rs = 0.0f;
            #pragma unroll
            for (int mf = 0; mf < 4; ++mf) {
                float p0 = __expf(st[mf][qf][0] - mnew);
                float p1 = __expf(st[mf][qf][1] - mnew);
                float p2 = __expf(st[mf][qf][2] - mnew);
                float p3 = __expf(st[mf][qf][3] - mnew);
                rs += (p0 + p1) + (p2 + p3);
                half4 ph; ph[0]=(_Float16)p0; ph[1]=(_Float16)p1;
                          ph[2]=(_Float16)p2; ph[3]=(_Float16)p3;
                *(half4*)&Pl[wid][ln + 16*qf][16*mf + 4*g] = ph;
            }
            rs += __shfl_xor(rs, 16);
            rs += __shfl_xor(rs, 32);
            l_i[qf] = l_i[qf]*alpha + rs;
            m_i[qf] = mnew;
            al[qf]  = alpha;
        }

        // ---- rescale O by alpha (redistribute: softmax lane-layout -> O rows) ----
        #pragma unroll
        for (int Mf = 0; Mf < 2; ++Mf)
            #pragma unroll
            for (int r = 0; r < 4; ++r) {
                const float a = __shfl(al[Mf], 4*g + r);
                #pragma unroll
                for (int nf = 0; nf < 4; ++nf) o[Mf][nf][r] *= a;
            }

        // ---- O += P . V ----
        #pragma unroll
        for (int ks = 0; ks < 2; ++ks) {
            half8 pa[2], vb[4];
            #pragma unroll
            for (int Mf = 0; Mf < 2; ++Mf)
                pa[Mf] = *(const half8*)&Pl[wid][ln + 16*Mf][8*g + 32*ks];
            #pragma unroll
            for (int nf = 0; nf < 4; ++nf)
                vb[nf] = *(const half8*)&VsT[ln + 16*nf][8*g + 32*ks];
            #pragma unroll
            for (int Mf = 0; Mf < 2; ++Mf)
                #pragma unroll
                for (int nf = 0; nf < 4; ++nf)
                    o[Mf][nf] = MFMA16(pa[Mf], vb[nf], o[Mf][nf]);
        }
        __syncthreads();   // all waves done with Ks/VsT before restage
    }

    // ---- epilogue: normalize by l (redistributed) and write (B,T,E) ----
    #pragma unroll
    for (int Mf = 0; Mf < 2; ++Mf)
        #pragma unroll
        for (int r = 0; r < 4; ++r) {
            const float lq  = __shfl(l_i[Mf], 4*g + r);
            const float inv = 1.0f / lq;
            const int qrow = qbase + 16*Mf + 4*g + r;
            float* dst = Og + ((size_t)b*NT + qrow)*NE + h*ND;
            #pragma unroll
            for (int nf = 0; nf < 4; ++nf)
                dst[ln + 16*nf] = o[Mf][nf][r] * inv;
        }
}

// ============================================================================
// Kernel 3: out-projection GEMM: out = O * Wo^T + bias (fp32, unchanged).
// ============================================================================
__global__ __launch_bounds__(256)
void out_proj_kernel(const float* __restrict__ A,   // [8192][1024]
                     const float* __restrict__ W,   // [1024][1024]
                     const float* __restrict__ bias,
                     float* __restrict__ out)
{
    __shared__ float As[16][132];
    __shared__ float Bs[16][132];

    const int tid = threadIdx.x;
    const int m0 = blockIdx.x * 128;
    const int n0 = blockIdx.y * 128;
    const int ry = tid >> 4;
    const int tx = tid & 15;
    const int lr  = tid >> 2;
    const int lc4 = (tid & 3) * 4;

    float acc[8][8];
    #pragma unroll
    for (int i = 0; i < 8; ++i)
        #pragma unroll
        for (int j = 0; j < 8; ++j) acc[i][j] = 0.0f;

    for (int kt = 0; kt < NE; kt += 16) {
        float4 a0 = *(const float4*)(A + (size_t)(m0 + lr) * NE + kt + lc4);
        float4 a1 = *(const float4*)(A + (size_t)(m0 + 64 + lr) * NE + kt + lc4);
        float4 b0 = *(const float4*)(W + (size_t)(n0 + lr) * NE + kt + lc4);
        float4 b1 = *(const float4*)(W + (size_t)(n0 + 64 + lr) * NE + kt + lc4);
        As[lc4+0][lr]    = a0.x; As[lc4+1][lr]    = a0.y; As[lc4+2][lr]    = a0.z; As[lc4+3][lr]    = a0.w;
        As[lc4+0][64+lr] = a1.x; As[lc4+1][64+lr] = a1.y; As[lc4+2][64+lr] = a1.z; As[lc4+3][64+lr] = a1.w;
        Bs[lc4+0][lr]    = b0.x; Bs[lc4+1][lr]    = b0.y; Bs[lc4+2][lr]    = b0.z; Bs[lc4+3][lr]    = b0.w;
        Bs[lc4+0][64+lr] = b1.x; Bs[lc4+1][64+lr] = b1.y; Bs[lc4+2][64+lr] = b1.z; Bs[lc4+3][64+lr] = b1.w;
        __syncthreads();
        #pragma unroll
        for (int k = 0; k < 16; ++k) {
            float av[8], bv[8];
            *(float4*)&av[0] = *(const float4*)&As[k][ry*4];
            *(float4*)&av[4] = *(const float4*)&As[k][64 + ry*4];
            *(float4*)&bv[0] = *(const float4*)&Bs[k][tx*4];
            *(float4*)&bv[4] = *(const float4*)&Bs[k][64 + tx*4];
            #pragma unroll
            for (int i = 0; i < 8; ++i)
                #pragma unroll
                for (int j = 0; j < 8; ++j)
                    acc[i][j] = fmaf(av[i], bv[j], acc[i][j]);
        }
        __syncthreads();
    }

    #pragma unroll
    for (int i = 0; i < 8; ++i) {
        const int rr = (i < 4) ? (ry*4 + i) : (64 + ry*4 + (i - 4));
        const int m  = m0 + rr;
        float4 c0, c1;
        c0.x = acc[i][0] + bias[n0 + tx*4 + 0];
        c0.y = acc[i][1] + bias[n0 + tx*4 + 1];
        c0.z = acc[i][2] + bias[n0 + tx*4 + 2];
        c0.w = acc[i][3] + bias[n0 + tx*4 + 3];
        c1.x = acc[i][4] + bias[n0 + 64 + tx*4 + 0];
        c1.y = acc[i][5] + bias[n0 + 64 + tx*4 + 1];
        c1.z = acc[i][6] + bias[n0 + 64 + tx*4 + 2];
        c1.w = acc[i][7] + bias[n0 + 64 + tx*4 + 3];
        *(float4*)(out + (size_t)m*NE + n0 + tx*4)      = c0;
        *(float4*)(out + (size_t)m*NE + n0 + 64 + tx*4) = c1;
    }
}

extern "C" void kernel_launch(void* const* d_in, const int* in_sizes, int n_in,
                              void* d_out, int out_size, void* d_ws, size_t ws_size,
                              hipStream_t stream)
{
    const float* X   = (const float*)d_in[0];   // query   [4,2048,1024]
    const float* pos = (const float*)d_in[1];   // positions [4,2048,3]
    const float* Wi  = (const float*)d_in[2];   // in_proj_weight [3072,1024]
    const float* bi  = (const float*)d_in[3];   // in_proj_bias [3072]
    const float* Wo  = (const float*)d_in[4];   // out_proj_weight [1024,1024]
    const float* bo  = (const float*)d_in[5];   // out_proj_bias [1024]
    const float* fr  = (const float*)d_in[6];   // freqs [16,32,3]
    float* out = (float*)d_out;

    const size_t SZ = (size_t)NB * NH * NT * ND;   // 8,388,608 floats
    float* Qb = (float*)d_ws;
    float* Kb = Qb + SZ;
    float* Vb = Kb + SZ;
    float* Ob = Vb + SZ;

    qkv_rotary_kernel<<<dim3(64, 24), 256, 0, stream>>>(X, Wi, bi, pos, fr, Qb, Kb, Vb);
    attn_mfma_kernel <<<dim3(64, 16), 256, 0, stream>>>(Qb, Kb, Vb, Ob);
    out_proj_kernel  <<<dim3(64, 8),  256, 0, stream>>>(Ob, Wo, bo, out);
}

// Round 3
// 291.271 us; speedup vs baseline: 6.8540x; 3.5961x over previous
//
#include <hip/hip_runtime.h>
#include <math.h>

#define NB 4
#define NT 2048
#define NE 1024
#define NH 16
#define ND 64
#define NF 32

typedef _Float16 half8 __attribute__((ext_vector_type(8)));
typedef _Float16 half4 __attribute__((ext_vector_type(4)));
typedef float f32x4 __attribute__((ext_vector_type(4)));
#define MFMA16(a, b, c) __builtin_amdgcn_mfma_f32_16x16x32_f16(a, b, c, 0, 0, 0)

// ============================================================================
// Kernel 0: fp32 -> fp16 conversion of X, Wi, Wo (one pass, grid-stride).
// ============================================================================
__global__ __launch_bounds__(256)
void cvt_kernel(const float* __restrict__ X, const float* __restrict__ Wi,
                const float* __restrict__ Wo,
                _Float16* __restrict__ Xh, _Float16* __restrict__ Wih,
                _Float16* __restrict__ Woh)
{
    const size_t NX = (size_t)8388608, NWI = 3145728, NWO = 1048576;
    const size_t TOT = (NX + NWI + NWO) / 8;   // half8 groups
    for (size_t gidx = (size_t)blockIdx.x*256 + threadIdx.x; gidx < TOT;
         gidx += (size_t)gridDim.x*256) {
        size_t i = gidx*8;
        const float* src; _Float16* dst; size_t off;
        if (i < NX)            { src = X;  dst = Xh;  off = i; }
        else if (i < NX + NWI) { src = Wi; dst = Wih; off = i - NX; }
        else                   { src = Wo; dst = Woh; off = i - NX - NWI; }
        float4 a = *(const float4*)(src + off);
        float4 b = *(const float4*)(src + off + 4);
        half8 h;
        h[0]=(_Float16)a.x; h[1]=(_Float16)a.y; h[2]=(_Float16)a.z; h[3]=(_Float16)a.w;
        h[4]=(_Float16)b.x; h[5]=(_Float16)b.y; h[6]=(_Float16)b.z; h[7]=(_Float16)b.w;
        *(half8*)(dst + off) = h;
    }
}

// ============================================================================
// Kernel 1: fp16 MFMA GEMM  C = Xh * Wih^T (+bias), fused rotary epilogue,
// writes Qh(x1/8)/Kh/Vh fp16 in (B,H,T,D).
// 128x128 tile, BK=32, 4 waves 2x2 (each 64x64 = 4x4 frags of 16x16x32).
// LDS XOR-swizzled in 16B slots: phys_slot(row,k8) = row*4 + (k8^((row>>1)&3))
// -> 2-way (free) on both ds_write_b128 staging and ds_read_b128 frags.
// ============================================================================
__global__ __launch_bounds__(256)
void qkv_mfma_kernel(const _Float16* __restrict__ Ah,
                     const _Float16* __restrict__ Bh,
                     const float* __restrict__ bias,
                     const float* __restrict__ pos,
                     const float* __restrict__ freqs,
                     _Float16* __restrict__ Qh,
                     _Float16* __restrict__ Kh,
                     _Float16* __restrict__ Vh)
{
    __shared__ _Float16 Ash[128*32];
    __shared__ _Float16 Bsh[128*32];

    const int tid = threadIdx.x;
    const int wid = tid >> 6, lane = tid & 63;
    const int ln = lane & 15, g = lane >> 4;
    const int wrow = wid >> 1, wcol = wid & 1;
    const int m0 = blockIdx.x * 128, n0 = blockIdx.y * 128;

    // staging: thread owns phys slots tid and tid+256
    const int r0 = tid >> 2, s0 = tid & 3;
    const int k8 = s0 ^ ((r0 >> 1) & 3);      // same for row r0+64
    const _Float16* gA0 = Ah + (size_t)(m0 + r0)      * NE + k8*8;
    const _Float16* gA1 = Ah + (size_t)(m0 + r0 + 64) * NE + k8*8;
    const _Float16* gB0 = Bh + (size_t)(n0 + r0)      * NE + k8*8;
    const _Float16* gB1 = Bh + (size_t)(n0 + r0 + 64) * NE + k8*8;

    // frag-read xor term (row bits that matter are ln's)
    const int xr = g ^ ((ln >> 1) & 3);

    f32x4 acc[4][4];
    #pragma unroll
    for (int i = 0; i < 4; ++i)
        #pragma unroll
        for (int j = 0; j < 4; ++j) acc[i][j] = (f32x4){0.f,0.f,0.f,0.f};

    half8 va0 = *(const half8*)gA0;
    half8 va1 = *(const half8*)gA1;
    half8 vb0 = *(const half8*)gB0;
    half8 vb1 = *(const half8*)gB1;

    for (int kt = 0; kt < NE; kt += 32) {
        if (kt) __syncthreads();
        *(half8*)&Ash[tid*8]       = va0;
        *(half8*)&Ash[(tid+256)*8] = va1;
        *(half8*)&Bsh[tid*8]       = vb0;
        *(half8*)&Bsh[(tid+256)*8] = vb1;
        __syncthreads();
        const int kn = kt + 32;
        if (kn < NE) {   // prefetch next tile under the MFMA phase
            va0 = *(const half8*)(gA0 + kn);
            va1 = *(const half8*)(gA1 + kn);
            vb0 = *(const half8*)(gB0 + kn);
            vb1 = *(const half8*)(gB1 + kn);
        }
        half8 af[4], bf[4];
        #pragma unroll
        for (int mf = 0; mf < 4; ++mf)
            af[mf] = *(const half8*)&Ash[(wrow*64 + mf*16 + ln)*32 + xr*8];
        #pragma unroll
        for (int nf = 0; nf < 4; ++nf)
            bf[nf] = *(const half8*)&Bsh[(wcol*64 + nf*16 + ln)*32 + xr*8];
        #pragma unroll
        for (int mf = 0; mf < 4; ++mf)
            #pragma unroll
            for (int nf = 0; nf < 4; ++nf)
                acc[mf][nf] = MFMA16(af[mf], bf[nf], acc[mf][nf]);
    }

    // ---- epilogue: bias + rotary (q,k) + fp16 scatter into (B,H,T,D) ----
    const int sec = n0 >> 10;               // 0:q 1:k 2:v (uniform per block)
    _Float16* dst = (sec == 0) ? Qh : (sec == 1) ? Kh : Vh;

    float cb[4], fx[4], fy[4], fz[4];
    int hh[4], dd[4];
    #pragma unroll
    for (int nf = 0; nf < 4; ++nf) {
        const int col = n0 + wcol*64 + nf*16 + ln;
        cb[nf] = bias[col];
        const int e = col & 1023;
        hh[nf] = e >> 6; dd[nf] = e & 63;
        if (sec != 2) {
            const float* fq = freqs + ((size_t)hh[nf]*NF + (dd[nf] >> 1))*3;
            fx[nf] = fq[0]; fy[nf] = fq[1]; fz[nf] = fq[2];
        }
    }
    const float sgn = (ln & 1) ? 1.0f : -1.0f;
    const float qs  = (sec == 0) ? 0.125f : 1.0f;

    #pragma unroll
    for (int mf = 0; mf < 4; ++mf) {
        #pragma unroll
        for (int r = 0; r < 4; ++r) {
            const int m = m0 + wrow*64 + mf*16 + g*4 + r;
            const int b = m >> 11, t = m & 2047;
            if (sec == 2) {
                #pragma unroll
                for (int nf = 0; nf < 4; ++nf)
                    dst[((size_t)(b*NH + hh[nf])*NT + t)*ND + dd[nf]] =
                        (_Float16)(acc[mf][nf][r] + cb[nf]);
            } else {
                const float px = pos[(size_t)m*3 + 0];
                const float py = pos[(size_t)m*3 + 1];
                const float pz = pos[(size_t)m*3 + 2];
                #pragma unroll
                for (int nf = 0; nf < 4; ++nf) {
                    const float x  = acc[mf][nf][r] + cb[nf];
                    const float xo = __shfl_xor(x, 1);
                    const float ang = px*fx[nf] + py*fy[nf] + pz*fz[nf];
                    float sn, cs;
                    __sincosf(ang, &sn, &cs);
                    const float out = (x*cs + sgn*xo*sn) * qs;
                    dst[((size_t)(b*NH + hh[nf])*NT + t)*ND + dd[nf]] = (_Float16)out;
                }
            }
        }
    }
}

// ============================================================================
// Kernel 2: fp16-MFMA flash attention (fp16 in, fp16 out). Q pre-scaled.
// ============================================================================
__global__ __launch_bounds__(256)
void attn_mfma_kernel(const _Float16* __restrict__ Qg, const _Float16* __restrict__ Kg,
                      const _Float16* __restrict__ Vg, _Float16* __restrict__ Og)
{
    __shared__ _Float16 Ks[64][72];      // [key][d]
    __shared__ _Float16 VsT[64][72];     // [d][key]
    __shared__ _Float16 Pl[4][32][72];   // per-wave [q][key]

    const int tid  = threadIdx.x;
    const int wid  = tid >> 6;
    const int lane = tid & 63;
    const int ln   = lane & 15;
    const int g    = lane >> 4;
    const int bh   = blockIdx.x;
    const int qt   = blockIdx.y;
    const int b = bh >> 4, h = bh & 15;
    const _Float16* Qp = Qg + (size_t)bh * NT * ND;
    const _Float16* Kp = Kg + (size_t)bh * NT * ND;
    const _Float16* Vp = Vg + (size_t)bh * NT * ND;

    const int qbase = qt*128 + wid*32;

    half8 qfr[2][2];
    #pragma unroll
    for (int qf = 0; qf < 2; ++qf)
        #pragma unroll
        for (int ks = 0; ks < 2; ++ks)
            qfr[qf][ks] = *(const half8*)(Qp + (size_t)(qbase + 16*qf + ln)*ND + 32*ks + 8*g);

    f32x4 o[2][4];
    float m_i[2], l_i[2];
    #pragma unroll
    for (int qf = 0; qf < 2; ++qf) {
        m_i[qf] = -INFINITY; l_i[qf] = 0.0f;
        #pragma unroll
        for (int nf = 0; nf < 4; ++nf) o[qf][nf] = (f32x4){0.f,0.f,0.f,0.f};
    }

    const int sr  = tid >> 2;         // 0..63 staging row (key)
    const int sc0 = (tid & 3) * 16;   // staging col base

    for (int kt = 0; kt < NT; kt += 64) {
        {   // stage K (row-major) + V (transposed)
            const _Float16* kp = Kp + (size_t)(kt + sr)*ND + sc0;
            const _Float16* vp = Vp + (size_t)(kt + sr)*ND + sc0;
            *(half8*)&Ks[sr][sc0]     = *(const half8*)kp;
            *(half8*)&Ks[sr][sc0 + 8] = *(const half8*)(kp + 8);
            half8 v0 = *(const half8*)vp;
            half8 v1 = *(const half8*)(vp + 8);
            #pragma unroll
            for (int u = 0; u < 8; ++u) {
                VsT[sc0 + u][sr]     = v0[u];
                VsT[sc0 + 8 + u][sr] = v1[u];
            }
        }
        __syncthreads();

        // S^T = K . Q^T
        f32x4 st[4][2];
        #pragma unroll
        for (int mf = 0; mf < 4; ++mf)
            #pragma unroll
            for (int qf = 0; qf < 2; ++qf) st[mf][qf] = (f32x4){0.f,0.f,0.f,0.f};

        #pragma unroll
        for (int ks = 0; ks < 2; ++ks) {
            half8 kf[4];
            #pragma unroll
            for (int mf = 0; mf < 4; ++mf)
                kf[mf] = *(const half8*)&Ks[16*mf + ln][8*g + 32*ks];
            #pragma unroll
            for (int mf = 0; mf < 4; ++mf)
                #pragma unroll
                for (int qf = 0; qf < 2; ++qf)
                    st[mf][qf] = MFMA16(kf[mf], qfr[qf][ks], st[mf][qf]);
        }

        // online softmax
        float al[2];
        #pragma unroll
        for (int qf = 0; qf < 2; ++qf) {
            float rm = -INFINITY;
            #pragma unroll
            for (int mf = 0; mf < 4; ++mf)
                #pragma unroll
                for (int r = 0; r < 4; ++r) rm = fmaxf(rm, st[mf][qf][r]);
            rm = fmaxf(rm, __shfl_xor(rm, 16));
            rm = fmaxf(rm, __shfl_xor(rm, 32));
            const float mnew  = fmaxf(m_i[qf], rm);
            const float alpha = __expf(m_i[qf] - mnew);
            float rs = 0.0f;
            #pragma unroll
            for (int mf = 0; mf < 4; ++mf) {
                float p0 = __expf(st[mf][qf][0] - mnew);
                float p1 = __expf(st[mf][qf][1] - mnew);
                float p2 = __expf(st[mf][qf][2] - mnew);
                float p3 = __expf(st[mf][qf][3] - mnew);
                rs += (p0 + p1) + (p2 + p3);
                half4 ph; ph[0]=(_Float16)p0; ph[1]=(_Float16)p1;
                          ph[2]=(_Float16)p2; ph[3]=(_Float16)p3;
                *(half4*)&Pl[wid][ln + 16*qf][16*mf + 4*g] = ph;
            }
            rs += __shfl_xor(rs, 16);
            rs += __shfl_xor(rs, 32);
            l_i[qf] = l_i[qf]*alpha + rs;
            m_i[qf] = mnew;
            al[qf]  = alpha;
        }

        // rescale O
        #pragma unroll
        for (int Mf = 0; Mf < 2; ++Mf)
            #pragma unroll
            for (int r = 0; r < 4; ++r) {
                const float a = __shfl(al[Mf], 4*g + r);
                #pragma unroll
                for (int nf = 0; nf < 4; ++nf) o[Mf][nf][r] *= a;
            }

        // O += P . V
        #pragma unroll
        for (int ks = 0; ks < 2; ++ks) {
            half8 pa[2], vb[4];
            #pragma unroll
            for (int Mf = 0; Mf < 2; ++Mf)
                pa[Mf] = *(const half8*)&Pl[wid][ln + 16*Mf][8*g + 32*ks];
            #pragma unroll
            for (int nf = 0; nf < 4; ++nf)
                vb[nf] = *(const half8*)&VsT[ln + 16*nf][8*g + 32*ks];
            #pragma unroll
            for (int Mf = 0; Mf < 2; ++Mf)
                #pragma unroll
                for (int nf = 0; nf < 4; ++nf)
                    o[Mf][nf] = MFMA16(pa[Mf], vb[nf], o[Mf][nf]);
        }
        __syncthreads();
    }

    // epilogue: normalize, write fp16 O in (B,T,E)
    #pragma unroll
    for (int Mf = 0; Mf < 2; ++Mf)
        #pragma unroll
        for (int r = 0; r < 4; ++r) {
            const float lq  = __shfl(l_i[Mf], 4*g + r);
            const float inv = 1.0f / lq;
            const int qrow = qbase + 16*Mf + 4*g + r;
            _Float16* dstp = Og + ((size_t)b*NT + qrow)*NE + h*ND;
            #pragma unroll
            for (int nf = 0; nf < 4; ++nf)
                dstp[ln + 16*nf] = (_Float16)(o[Mf][nf][r] * inv);
        }
}

// ============================================================================
// Kernel 3: fp16 MFMA out-projection: out(f32) = Oh * Woh^T + bias.
// Same tile/swizzle template as kernel 1.
// ============================================================================
__global__ __launch_bounds__(256)
void out_proj_mfma_kernel(const _Float16* __restrict__ Ah,
                          const _Float16* __restrict__ Bh,
                          const float* __restrict__ bias,
                          float* __restrict__ out)
{
    __shared__ _Float16 Ash[128*32];
    __shared__ _Float16 Bsh[128*32];

    const int tid = threadIdx.x;
    const int wid = tid >> 6, lane = tid & 63;
    const int ln = lane & 15, g = lane >> 4;
    const int wrow = wid >> 1, wcol = wid & 1;
    const int m0 = blockIdx.x * 128, n0 = blockIdx.y * 128;

    const int r0 = tid >> 2, s0 = tid & 3;
    const int k8 = s0 ^ ((r0 >> 1) & 3);
    const _Float16* gA0 = Ah + (size_t)(m0 + r0)      * NE + k8*8;
    const _Float16* gA1 = Ah + (size_t)(m0 + r0 + 64) * NE + k8*8;
    const _Float16* gB0 = Bh + (size_t)(n0 + r0)      * NE + k8*8;
    const _Float16* gB1 = Bh + (size_t)(n0 + r0 + 64) * NE + k8*8;
    const int xr = g ^ ((ln >> 1) & 3);

    f32x4 acc[4][4];
    #pragma unroll
    for (int i = 0; i < 4; ++i)
        #pragma unroll
        for (int j = 0; j < 4; ++j) acc[i][j] = (f32x4){0.f,0.f,0.f,0.f};

    half8 va0 = *(const half8*)gA0;
    half8 va1 = *(const half8*)gA1;
    half8 vb0 = *(const half8*)gB0;
    half8 vb1 = *(const half8*)gB1;

    for (int kt = 0; kt < NE; kt += 32) {
        if (kt) __syncthreads();
        *(half8*)&Ash[tid*8]       = va0;
        *(half8*)&Ash[(tid+256)*8] = va1;
        *(half8*)&Bsh[tid*8]       = vb0;
        *(half8*)&Bsh[(tid+256)*8] = vb1;
        __syncthreads();
        const int kn = kt + 32;
        if (kn < NE) {
            va0 = *(const half8*)(gA0 + kn);
            va1 = *(const half8*)(gA1 + kn);
            vb0 = *(const half8*)(gB0 + kn);
            vb1 = *(const half8*)(gB1 + kn);
        }
        half8 af[4], bf[4];
        #pragma unroll
        for (int mf = 0; mf < 4; ++mf)
            af[mf] = *(const half8*)&Ash[(wrow*64 + mf*16 + ln)*32 + xr*8];
        #pragma unroll
        for (int nf = 0; nf < 4; ++nf)
            bf[nf] = *(const half8*)&Bsh[(wcol*64 + nf*16 + ln)*32 + xr*8];
        #pragma unroll
        for (int mf = 0; mf < 4; ++mf)
            #pragma unroll
            for (int nf = 0; nf < 4; ++nf)
                acc[mf][nf] = MFMA16(af[mf], bf[nf], acc[mf][nf]);
    }

    float cb[4];
    #pragma unroll
    for (int nf = 0; nf < 4; ++nf) cb[nf] = bias[n0 + wcol*64 + nf*16 + ln];

    #pragma unroll
    for (int mf = 0; mf < 4; ++mf)
        #pragma unroll
        for (int r = 0; r < 4; ++r) {
            const int m = m0 + wrow*64 + mf*16 + g*4 + r;
            #pragma unroll
            for (int nf = 0; nf < 4; ++nf)
                out[(size_t)m*NE + n0 + wcol*64 + nf*16 + ln] = acc[mf][nf][r] + cb[nf];
        }
}

extern "C" void kernel_launch(void* const* d_in, const int* in_sizes, int n_in,
                              void* d_out, int out_size, void* d_ws, size_t ws_size,
                              hipStream_t stream)
{
    const float* X   = (const float*)d_in[0];
    const float* pos = (const float*)d_in[1];
    const float* Wi  = (const float*)d_in[2];
    const float* bi  = (const float*)d_in[3];
    const float* Wo  = (const float*)d_in[4];
    const float* bo  = (const float*)d_in[5];
    const float* fr  = (const float*)d_in[6];
    float* out = (float*)d_out;

    _Float16* Xh  = (_Float16*)d_ws;            // 8388608
    _Float16* Wih = Xh  + 8388608;              // 3145728
    _Float16* Woh = Wih + 3145728;              // 1048576
    _Float16* Qh  = Woh + 1048576;              // 8388608
    _Float16* Kh  = Qh  + 8388608;
    _Float16* Vh  = Kh  + 8388608;
    _Float16* Oh  = Vh  + 8388608;

    cvt_kernel          <<<3072, 256, 0, stream>>>(X, Wi, Wo, Xh, Wih, Woh);
    qkv_mfma_kernel     <<<dim3(64, 24), 256, 0, stream>>>(Xh, Wih, bi, pos, fr, Qh, Kh, Vh);
    attn_mfma_kernel    <<<dim3(64, 16), 256, 0, stream>>>(Qh, Kh, Vh, Oh);
    out_proj_mfma_kernel<<<dim3(64, 8),  256, 0, stream>>>(Oh, Woh, bo, out);
}

// Round 4
// 268.000 us; speedup vs baseline: 7.4492x; 1.0868x over previous
//
#include <hip/hip_runtime.h>
#include <math.h>

#define NB 4
#define NT 2048
#define NE 1024
#define NH 16
#define ND 64
#define NF 32

typedef _Float16 half8 __attribute__((ext_vector_type(8)));
typedef _Float16 half4 __attribute__((ext_vector_type(4)));
typedef unsigned short ushort8v __attribute__((ext_vector_type(8)));
typedef float f32x4 __attribute__((ext_vector_type(4)));
#define MFMA16(a, b, c) __builtin_amdgcn_mfma_f32_16x16x32_f16(a, b, c, 0, 0, 0)

// ============================================================================
// Kernel 0: fp32 -> fp16 conversion of X, Wi, Wo (one pass, grid-stride).
// ============================================================================
__global__ __launch_bounds__(256)
void cvt_kernel(const float* __restrict__ X, const float* __restrict__ Wi,
                const float* __restrict__ Wo,
                _Float16* __restrict__ Xh, _Float16* __restrict__ Wih,
                _Float16* __restrict__ Woh)
{
    const size_t NX = (size_t)8388608, NWI = 3145728, NWO = 1048576;
    const size_t TOT = (NX + NWI + NWO) / 8;   // half8 groups
    for (size_t gidx = (size_t)blockIdx.x*256 + threadIdx.x; gidx < TOT;
         gidx += (size_t)gridDim.x*256) {
        size_t i = gidx*8;
        const float* src; _Float16* dst; size_t off;
        if (i < NX)            { src = X;  dst = Xh;  off = i; }
        else if (i < NX + NWI) { src = Wi; dst = Wih; off = i - NX; }
        else                   { src = Wo; dst = Woh; off = i - NX - NWI; }
        float4 a = *(const float4*)(src + off);
        float4 b = *(const float4*)(src + off + 4);
        half8 h;
        h[0]=(_Float16)a.x; h[1]=(_Float16)a.y; h[2]=(_Float16)a.z; h[3]=(_Float16)a.w;
        h[4]=(_Float16)b.x; h[5]=(_Float16)b.y; h[6]=(_Float16)b.z; h[7]=(_Float16)b.w;
        *(half8*)(dst + off) = h;
    }
}

// ============================================================================
// Kernel 1: fp16 MFMA GEMM  C = Xh * Wih^T (+bias), fused rotary epilogue,
// writes Qh(x1/8)/Kh/Vh fp16 in (B,H,T,D). (unchanged from R3)
// ============================================================================
__global__ __launch_bounds__(256)
void qkv_mfma_kernel(const _Float16* __restrict__ Ah,
                     const _Float16* __restrict__ Bh,
                     const float* __restrict__ bias,
                     const float* __restrict__ pos,
                     const float* __restrict__ freqs,
                     _Float16* __restrict__ Qh,
                     _Float16* __restrict__ Kh,
                     _Float16* __restrict__ Vh)
{
    __shared__ _Float16 Ash[128*32];
    __shared__ _Float16 Bsh[128*32];

    const int tid = threadIdx.x;
    const int wid = tid >> 6, lane = tid & 63;
    const int ln = lane & 15, g = lane >> 4;
    const int wrow = wid >> 1, wcol = wid & 1;
    const int m0 = blockIdx.x * 128, n0 = blockIdx.y * 128;

    const int r0 = tid >> 2, s0 = tid & 3;
    const int k8 = s0 ^ ((r0 >> 1) & 3);
    const _Float16* gA0 = Ah + (size_t)(m0 + r0)      * NE + k8*8;
    const _Float16* gA1 = Ah + (size_t)(m0 + r0 + 64) * NE + k8*8;
    const _Float16* gB0 = Bh + (size_t)(n0 + r0)      * NE + k8*8;
    const _Float16* gB1 = Bh + (size_t)(n0 + r0 + 64) * NE + k8*8;

    const int xr = g ^ ((ln >> 1) & 3);

    f32x4 acc[4][4];
    #pragma unroll
    for (int i = 0; i < 4; ++i)
        #pragma unroll
        for (int j = 0; j < 4; ++j) acc[i][j] = (f32x4){0.f,0.f,0.f,0.f};

    half8 va0 = *(const half8*)gA0;
    half8 va1 = *(const half8*)gA1;
    half8 vb0 = *(const half8*)gB0;
    half8 vb1 = *(const half8*)gB1;

    for (int kt = 0; kt < NE; kt += 32) {
        if (kt) __syncthreads();
        *(half8*)&Ash[tid*8]       = va0;
        *(half8*)&Ash[(tid+256)*8] = va1;
        *(half8*)&Bsh[tid*8]       = vb0;
        *(half8*)&Bsh[(tid+256)*8] = vb1;
        __syncthreads();
        const int kn = kt + 32;
        if (kn < NE) {
            va0 = *(const half8*)(gA0 + kn);
            va1 = *(const half8*)(gA1 + kn);
            vb0 = *(const half8*)(gB0 + kn);
            vb1 = *(const half8*)(gB1 + kn);
        }
        half8 af[4], bf[4];
        #pragma unroll
        for (int mf = 0; mf < 4; ++mf)
            af[mf] = *(const half8*)&Ash[(wrow*64 + mf*16 + ln)*32 + xr*8];
        #pragma unroll
        for (int nf = 0; nf < 4; ++nf)
            bf[nf] = *(const half8*)&Bsh[(wcol*64 + nf*16 + ln)*32 + xr*8];
        __builtin_amdgcn_s_setprio(1);
        #pragma unroll
        for (int mf = 0; mf < 4; ++mf)
            #pragma unroll
            for (int nf = 0; nf < 4; ++nf)
                acc[mf][nf] = MFMA16(af[mf], bf[nf], acc[mf][nf]);
        __builtin_amdgcn_s_setprio(0);
    }

    const int sec = n0 >> 10;
    _Float16* dst = (sec == 0) ? Qh : (sec == 1) ? Kh : Vh;

    float cb[4], fx[4], fy[4], fz[4];
    int hh[4], dd[4];
    #pragma unroll
    for (int nf = 0; nf < 4; ++nf) {
        const int col = n0 + wcol*64 + nf*16 + ln;
        cb[nf] = bias[col];
        const int e = col & 1023;
        hh[nf] = e >> 6; dd[nf] = e & 63;
        if (sec != 2) {
            const float* fq = freqs + ((size_t)hh[nf]*NF + (dd[nf] >> 1))*3;
            fx[nf] = fq[0]; fy[nf] = fq[1]; fz[nf] = fq[2];
        }
    }
    const float sgn = (ln & 1) ? 1.0f : -1.0f;
    const float qs  = (sec == 0) ? 0.125f : 1.0f;

    #pragma unroll
    for (int mf = 0; mf < 4; ++mf) {
        #pragma unroll
        for (int r = 0; r < 4; ++r) {
            const int m = m0 + wrow*64 + mf*16 + g*4 + r;
            const int b = m >> 11, t = m & 2047;
            if (sec == 2) {
                #pragma unroll
                for (int nf = 0; nf < 4; ++nf)
                    dst[((size_t)(b*NH + hh[nf])*NT + t)*ND + dd[nf]] =
                        (_Float16)(acc[mf][nf][r] + cb[nf]);
            } else {
                const float px = pos[(size_t)m*3 + 0];
                const float py = pos[(size_t)m*3 + 1];
                const float pz = pos[(size_t)m*3 + 2];
                #pragma unroll
                for (int nf = 0; nf < 4; ++nf) {
                    const float x  = acc[mf][nf][r] + cb[nf];
                    const float xo = __shfl_xor(x, 1);
                    const float ang = px*fx[nf] + py*fy[nf] + pz*fz[nf];
                    float sn, cs;
                    __sincosf(ang, &sn, &cs);
                    const float out = (x*cs + sgn*xo*sn) * qs;
                    dst[((size_t)(b*NH + hh[nf])*NT + t)*ND + dd[nf]] = (_Float16)out;
                }
            }
        }
    }
}

// ============================================================================
// Kernel 2: fp16-MFMA flash attention (fp16 in, fp16 out). Q pre-scaled.
// R4: V transposed at the GLOBAL read (b32 column-pair loads, coalesced;
// b128 conflict-free LDS writes) -- removes the 2.7e7 bank conflicts from the
// old scalar transpose-on-write. K+V next-tile regs prefetched under compute
// (T14). s_setprio around MFMA clusters (T5).
// ============================================================================
__global__ __launch_bounds__(256)
void attn_mfma_kernel(const _Float16* __restrict__ Qg, const _Float16* __restrict__ Kg,
                      const _Float16* __restrict__ Vg, _Float16* __restrict__ Og)
{
    __shared__ _Float16 Ks[64][72];      // [key][d]
    __shared__ _Float16 VsT[64][72];     // [d][key]
    __shared__ _Float16 Pl[4][32][72];   // per-wave [q][key]

    const int tid  = threadIdx.x;
    const int wid  = tid >> 6;
    const int lane = tid & 63;
    const int ln   = lane & 15;
    const int g    = lane >> 4;
    const int bh   = blockIdx.x;
    const int qt   = blockIdx.y;
    const int b = bh >> 4, h = bh & 15;
    const _Float16* Qp = Qg + (size_t)bh * NT * ND;
    const _Float16* Kp = Kg + (size_t)bh * NT * ND;
    const _Float16* Vp = Vg + (size_t)bh * NT * ND;

    const int qbase = qt*128 + wid*32;

    half8 qfr[2][2];
    #pragma unroll
    for (int qf = 0; qf < 2; ++qf)
        #pragma unroll
        for (int ks = 0; ks < 2; ++ks)
            qfr[qf][ks] = *(const half8*)(Qp + (size_t)(qbase + 16*qf + ln)*ND + 32*ks + 8*g);

    f32x4 o[2][4];
    float m_i[2], l_i[2];
    #pragma unroll
    for (int qf = 0; qf < 2; ++qf) {
        m_i[qf] = -INFINITY; l_i[qf] = 0.0f;
        #pragma unroll
        for (int nf = 0; nf < 4; ++nf) o[qf][nf] = (f32x4){0.f,0.f,0.f,0.f};
    }

    // staging geometry
    const int sr  = tid >> 2;            // K: key row 0..63
    const int sc0 = (tid & 3) * 16;      // K: d col base
    const int dp  = tid & 31;            // V: dword index (d = 2dp, 2dp+1)
    const int wv  = tid >> 5;            // V: key group 0..7 (8 keys each)
    const _Float16* kbase = Kp + (size_t)sr*ND + sc0;
    const _Float16* vbase = Vp + (size_t)(wv*8)*ND + 2*dp;

    // prologue: load tile 0 into regs
    half8 kv0 = *(const half8*)(kbase);
    half8 kv1 = *(const half8*)(kbase + 8);
    unsigned int vr[8];
    #pragma unroll
    for (int j = 0; j < 8; ++j)
        vr[j] = *(const unsigned int*)(vbase + (size_t)j*ND);

    for (int kt = 0; kt < NT; kt += 64) {
        if (kt) __syncthreads();
        // ---- write staged regs to LDS ----
        *(half8*)&Ks[sr][sc0]     = kv0;
        *(half8*)&Ks[sr][sc0 + 8] = kv1;
        {
            ushort8v lo, hi;
            #pragma unroll
            for (int j = 0; j < 8; ++j) {
                lo[j] = (unsigned short)(vr[j] & 0xffffu);
                hi[j] = (unsigned short)(vr[j] >> 16);
            }
            *(ushort8v*)&VsT[2*dp][wv*8]     = lo;
            *(ushort8v*)&VsT[2*dp + 1][wv*8] = hi;
        }
        __syncthreads();

        // ---- prefetch next tile into regs (hides under compute) ----
        const int kn = kt + 64;
        if (kn < NT) {
            kv0 = *(const half8*)(kbase + (size_t)kn*ND);
            kv1 = *(const half8*)(kbase + (size_t)kn*ND + 8);
            #pragma unroll
            for (int j = 0; j < 8; ++j)
                vr[j] = *(const unsigned int*)(vbase + (size_t)(kn + j)*ND);
        }

        // ---- S^T = K . Q^T ----
        f32x4 st[4][2];
        #pragma unroll
        for (int mf = 0; mf < 4; ++mf)
            #pragma unroll
            for (int qf = 0; qf < 2; ++qf) st[mf][qf] = (f32x4){0.f,0.f,0.f,0.f};

        __builtin_amdgcn_s_setprio(1);
        #pragma unroll
        for (int ks = 0; ks < 2; ++ks) {
            half8 kf[4];
            #pragma unroll
            for (int mf = 0; mf < 4; ++mf)
                kf[mf] = *(const half8*)&Ks[16*mf + ln][8*g + 32*ks];
            #pragma unroll
            for (int mf = 0; mf < 4; ++mf)
                #pragma unroll
                for (int qf = 0; qf < 2; ++qf)
                    st[mf][qf] = MFMA16(kf[mf], qfr[qf][ks], st[mf][qf]);
        }
        __builtin_amdgcn_s_setprio(0);

        // ---- online softmax ----
        float al[2];
        #pragma unroll
        for (int qf = 0; qf < 2; ++qf) {
            float rm = -INFINITY;
            #pragma unroll
            for (int mf = 0; mf < 4; ++mf)
                #pragma unroll
                for (int r = 0; r < 4; ++r) rm = fmaxf(rm, st[mf][qf][r]);
            rm = fmaxf(rm, __shfl_xor(rm, 16));
            rm = fmaxf(rm, __shfl_xor(rm, 32));
            const float mnew  = fmaxf(m_i[qf], rm);
            const float alpha = __expf(m_i[qf] - mnew);
            float rs = 0.0f;
            #pragma unroll
            for (int mf = 0; mf < 4; ++mf) {
                float p0 = __expf(st[mf][qf][0] - mnew);
                float p1 = __expf(st[mf][qf][1] - mnew);
                float p2 = __expf(st[mf][qf][2] - mnew);
                float p3 = __expf(st[mf][qf][3] - mnew);
                rs += (p0 + p1) + (p2 + p3);
                half4 ph; ph[0]=(_Float16)p0; ph[1]=(_Float16)p1;
                          ph[2]=(_Float16)p2; ph[3]=(_Float16)p3;
                *(half4*)&Pl[wid][ln + 16*qf][16*mf + 4*g] = ph;
            }
            rs += __shfl_xor(rs, 16);
            rs += __shfl_xor(rs, 32);
            l_i[qf] = l_i[qf]*alpha + rs;
            m_i[qf] = mnew;
            al[qf]  = alpha;
        }

        // ---- rescale O ----
        #pragma unroll
        for (int Mf = 0; Mf < 2; ++Mf)
            #pragma unroll
            for (int r = 0; r < 4; ++r) {
                const float a = __shfl(al[Mf], 4*g + r);
                #pragma unroll
                for (int nf = 0; nf < 4; ++nf) o[Mf][nf][r] *= a;
            }

        // ---- O += P . V ----
        __builtin_amdgcn_s_setprio(1);
        #pragma unroll
        for (int ks = 0; ks < 2; ++ks) {
            half8 pa[2], vb[4];
            #pragma unroll
            for (int Mf = 0; Mf < 2; ++Mf)
                pa[Mf] = *(const half8*)&Pl[wid][ln + 16*Mf][8*g + 32*ks];
            #pragma unroll
            for (int nf = 0; nf < 4; ++nf)
                vb[nf] = *(const half8*)&VsT[ln + 16*nf][8*g + 32*ks];
            #pragma unroll
            for (int Mf = 0; Mf < 2; ++Mf)
                #pragma unroll
                for (int nf = 0; nf < 4; ++nf)
                    o[Mf][nf] = MFMA16(pa[Mf], vb[nf], o[Mf][nf]);
        }
        __builtin_amdgcn_s_setprio(0);
        __syncthreads();
    }

    // epilogue: normalize, write fp16 O in (B,T,E)
    #pragma unroll
    for (int Mf = 0; Mf < 2; ++Mf)
        #pragma unroll
        for (int r = 0; r < 4; ++r) {
            const float lq  = __shfl(l_i[Mf], 4*g + r);
            const float inv = 1.0f / lq;
            const int qrow = qbase + 16*Mf + 4*g + r;
            _Float16* dstp = Og + ((size_t)b*NT + qrow)*NE + h*ND;
            #pragma unroll
            for (int nf = 0; nf < 4; ++nf)
                dstp[ln + 16*nf] = (_Float16)(o[Mf][nf][r] * inv);
        }
}

// ============================================================================
// Kernel 3: fp16 MFMA out-projection: out(f32) = Oh * Woh^T + bias.
// ============================================================================
__global__ __launch_bounds__(256)
void out_proj_mfma_kernel(const _Float16* __restrict__ Ah,
                          const _Float16* __restrict__ Bh,
                          const float* __restrict__ bias,
                          float* __restrict__ out)
{
    __shared__ _Float16 Ash[128*32];
    __shared__ _Float16 Bsh[128*32];

    const int tid = threadIdx.x;
    const int wid = tid >> 6, lane = tid & 63;
    const int ln = lane & 15, g = lane >> 4;
    const int wrow = wid >> 1, wcol = wid & 1;
    const int m0 = blockIdx.x * 128, n0 = blockIdx.y * 128;

    const int r0 = tid >> 2, s0 = tid & 3;
    const int k8 = s0 ^ ((r0 >> 1) & 3);
    const _Float16* gA0 = Ah + (size_t)(m0 + r0)      * NE + k8*8;
    const _Float16* gA1 = Ah + (size_t)(m0 + r0 + 64) * NE + k8*8;
    const _Float16* gB0 = Bh + (size_t)(n0 + r0)      * NE + k8*8;
    const _Float16* gB1 = Bh + (size_t)(n0 + r0 + 64) * NE + k8*8;
    const int xr = g ^ ((ln >> 1) & 3);

    f32x4 acc[4][4];
    #pragma unroll
    for (int i = 0; i < 4; ++i)
        #pragma unroll
        for (int j = 0; j < 4; ++j) acc[i][j] = (f32x4){0.f,0.f,0.f,0.f};

    half8 va0 = *(const half8*)gA0;
    half8 va1 = *(const half8*)gA1;
    half8 vb0 = *(const half8*)gB0;
    half8 vb1 = *(const half8*)gB1;

    for (int kt = 0; kt < NE; kt += 32) {
        if (kt) __syncthreads();
        *(half8*)&Ash[tid*8]       = va0;
        *(half8*)&Ash[(tid+256)*8] = va1;
        *(half8*)&Bsh[tid*8]       = vb0;
        *(half8*)&Bsh[(tid+256)*8] = vb1;
        __syncthreads();
        const int kn = kt + 32;
        if (kn < NE) {
            va0 = *(const half8*)(gA0 + kn);
            va1 = *(const half8*)(gA1 + kn);
            vb0 = *(const half8*)(gB0 + kn);
            vb1 = *(const half8*)(gB1 + kn);
        }
        half8 af[4], bf[4];
        #pragma unroll
        for (int mf = 0; mf < 4; ++mf)
            af[mf] = *(const half8*)&Ash[(wrow*64 + mf*16 + ln)*32 + xr*8];
        #pragma unroll
        for (int nf = 0; nf < 4; ++nf)
            bf[nf] = *(const half8*)&Bsh[(wcol*64 + nf*16 + ln)*32 + xr*8];
        __builtin_amdgcn_s_setprio(1);
        #pragma unroll
        for (int mf = 0; mf < 4; ++mf)
            #pragma unroll
            for (int nf = 0; nf < 4; ++nf)
                acc[mf][nf] = MFMA16(af[mf], bf[nf], acc[mf][nf]);
        __builtin_amdgcn_s_setprio(0);
    }

    float cb[4];
    #pragma unroll
    for (int nf = 0; nf < 4; ++nf) cb[nf] = bias[n0 + wcol*64 + nf*16 + ln];

    #pragma unroll
    for (int mf = 0; mf < 4; ++mf)
        #pragma unroll
        for (int r = 0; r < 4; ++r) {
            const int m = m0 + wrow*64 + mf*16 + g*4 + r;
            #pragma unroll
            for (int nf = 0; nf < 4; ++nf)
                out[(size_t)m*NE + n0 + wcol*64 + nf*16 + ln] = acc[mf][nf][r] + cb[nf];
        }
}

extern "C" void kernel_launch(void* const* d_in, const int* in_sizes, int n_in,
                              void* d_out, int out_size, void* d_ws, size_t ws_size,
                              hipStream_t stream)
{
    const float* X   = (const float*)d_in[0];
    const float* pos = (const float*)d_in[1];
    const float* Wi  = (const float*)d_in[2];
    const float* bi  = (const float*)d_in[3];
    const float* Wo  = (const float*)d_in[4];
    const float* bo  = (const float*)d_in[5];
    const float* fr  = (const float*)d_in[6];
    float* out = (float*)d_out;

    _Float16* Xh  = (_Float16*)d_ws;            // 8388608
    _Float16* Wih = Xh  + 8388608;              // 3145728
    _Float16* Woh = Wih + 3145728;              // 1048576
    _Float16* Qh  = Woh + 1048576;              // 8388608
    _Float16* Kh  = Qh  + 8388608;
    _Float16* Vh  = Kh  + 8388608;
    _Float16* Oh  = Vh  + 8388608;

    cvt_kernel          <<<3072, 256, 0, stream>>>(X, Wi, Wo, Xh, Wih, Woh);
    qkv_mfma_kernel     <<<dim3(64, 24), 256, 0, stream>>>(Xh, Wih, bi, pos, fr, Qh, Kh, Vh);
    attn_mfma_kernel    <<<dim3(64, 16), 256, 0, stream>>>(Qh, Kh, Vh, Oh);
    out_proj_mfma_kernel<<<dim3(64, 8),  256, 0, stream>>>(Oh, Woh, bo, out);
}

// Round 5
// 250.961 us; speedup vs baseline: 7.9550x; 1.0679x over previous
//
#include <hip/hip_runtime.h>
#include <math.h>

#define NB 4
#define NT 2048
#define NE 1024
#define NH 16
#define ND 64
#define NF 32

typedef _Float16 half8 __attribute__((ext_vector_type(8)));
typedef _Float16 half4 __attribute__((ext_vector_type(4)));
typedef _Float16 half2v __attribute__((ext_vector_type(2)));
typedef unsigned short ushort8v __attribute__((ext_vector_type(8)));
typedef unsigned int uint4v __attribute__((ext_vector_type(4)));
typedef float f32x4 __attribute__((ext_vector_type(4)));
typedef float f32x16 __attribute__((ext_vector_type(16)));
#define MFMA16(a, b, c) __builtin_amdgcn_mfma_f32_16x16x32_f16(a, b, c, 0, 0, 0)
#define MFMA32(a, b, c) __builtin_amdgcn_mfma_f32_32x32x16_f16(a, b, c, 0, 0, 0)

__device__ __forceinline__ float fast_exp2(float x) {
    float r;
    asm volatile("v_exp_f32 %0, %1" : "=v"(r) : "v"(x));
    return r;
}

// ============================================================================
// Kernel 0: fp32 -> fp16 conversion of X, Wi, Wo (one pass, grid-stride).
// ============================================================================
__global__ __launch_bounds__(256)
void cvt_kernel(const float* __restrict__ X, const float* __restrict__ Wi,
                const float* __restrict__ Wo,
                _Float16* __restrict__ Xh, _Float16* __restrict__ Wih,
                _Float16* __restrict__ Woh)
{
    const size_t NX = (size_t)8388608, NWI = 3145728, NWO = 1048576;
    const size_t TOT = (NX + NWI + NWO) / 8;   // half8 groups
    for (size_t gidx = (size_t)blockIdx.x*256 + threadIdx.x; gidx < TOT;
         gidx += (size_t)gridDim.x*256) {
        size_t i = gidx*8;
        const float* src; _Float16* dst; size_t off;
        if (i < NX)            { src = X;  dst = Xh;  off = i; }
        else if (i < NX + NWI) { src = Wi; dst = Wih; off = i - NX; }
        else                   { src = Wo; dst = Woh; off = i - NX - NWI; }
        float4 a = *(const float4*)(src + off);
        float4 b = *(const float4*)(src + off + 4);
        half8 h;
        h[0]=(_Float16)a.x; h[1]=(_Float16)a.y; h[2]=(_Float16)a.z; h[3]=(_Float16)a.w;
        h[4]=(_Float16)b.x; h[5]=(_Float16)b.y; h[6]=(_Float16)b.z; h[7]=(_Float16)b.w;
        *(half8*)(dst + off) = h;
    }
}

// ============================================================================
// Kernel 1: fp16 MFMA GEMM  C = Xh * Wih^T (+bias), fused rotary epilogue.
// Q additionally scaled by (1/8)*log2(e) so attention runs in exp2 domain.
// ============================================================================
__global__ __launch_bounds__(256)
void qkv_mfma_kernel(const _Float16* __restrict__ Ah,
                     const _Float16* __restrict__ Bh,
                     const float* __restrict__ bias,
                     const float* __restrict__ pos,
                     const float* __restrict__ freqs,
                     _Float16* __restrict__ Qh,
                     _Float16* __restrict__ Kh,
                     _Float16* __restrict__ Vh)
{
    __shared__ _Float16 Ash[128*32];
    __shared__ _Float16 Bsh[128*32];

    const int tid = threadIdx.x;
    const int wid = tid >> 6, lane = tid & 63;
    const int ln = lane & 15, g = lane >> 4;
    const int wrow = wid >> 1, wcol = wid & 1;
    const int m0 = blockIdx.x * 128, n0 = blockIdx.y * 128;

    const int r0 = tid >> 2, s0 = tid & 3;
    const int k8 = s0 ^ ((r0 >> 1) & 3);
    const _Float16* gA0 = Ah + (size_t)(m0 + r0)      * NE + k8*8;
    const _Float16* gA1 = Ah + (size_t)(m0 + r0 + 64) * NE + k8*8;
    const _Float16* gB0 = Bh + (size_t)(n0 + r0)      * NE + k8*8;
    const _Float16* gB1 = Bh + (size_t)(n0 + r0 + 64) * NE + k8*8;

    const int xr = g ^ ((ln >> 1) & 3);

    f32x4 acc[4][4];
    #pragma unroll
    for (int i = 0; i < 4; ++i)
        #pragma unroll
        for (int j = 0; j < 4; ++j) acc[i][j] = (f32x4){0.f,0.f,0.f,0.f};

    half8 va0 = *(const half8*)gA0;
    half8 va1 = *(const half8*)gA1;
    half8 vb0 = *(const half8*)gB0;
    half8 vb1 = *(const half8*)gB1;

    for (int kt = 0; kt < NE; kt += 32) {
        if (kt) __syncthreads();
        *(half8*)&Ash[tid*8]       = va0;
        *(half8*)&Ash[(tid+256)*8] = va1;
        *(half8*)&Bsh[tid*8]       = vb0;
        *(half8*)&Bsh[(tid+256)*8] = vb1;
        __syncthreads();
        const int kn = kt + 32;
        if (kn < NE) {
            va0 = *(const half8*)(gA0 + kn);
            va1 = *(const half8*)(gA1 + kn);
            vb0 = *(const half8*)(gB0 + kn);
            vb1 = *(const half8*)(gB1 + kn);
        }
        half8 af[4], bf[4];
        #pragma unroll
        for (int mf = 0; mf < 4; ++mf)
            af[mf] = *(const half8*)&Ash[(wrow*64 + mf*16 + ln)*32 + xr*8];
        #pragma unroll
        for (int nf = 0; nf < 4; ++nf)
            bf[nf] = *(const half8*)&Bsh[(wcol*64 + nf*16 + ln)*32 + xr*8];
        __builtin_amdgcn_s_setprio(1);
        #pragma unroll
        for (int mf = 0; mf < 4; ++mf)
            #pragma unroll
            for (int nf = 0; nf < 4; ++nf)
                acc[mf][nf] = MFMA16(af[mf], bf[nf], acc[mf][nf]);
        __builtin_amdgcn_s_setprio(0);
    }

    const int sec = n0 >> 10;
    _Float16* dst = (sec == 0) ? Qh : (sec == 1) ? Kh : Vh;

    float cb[4], fx[4], fy[4], fz[4];
    int hh[4], dd[4];
    #pragma unroll
    for (int nf = 0; nf < 4; ++nf) {
        const int col = n0 + wcol*64 + nf*16 + ln;
        cb[nf] = bias[col];
        const int e = col & 1023;
        hh[nf] = e >> 6; dd[nf] = e & 63;
        if (sec != 2) {
            const float* fq = freqs + ((size_t)hh[nf]*NF + (dd[nf] >> 1))*3;
            fx[nf] = fq[0]; fy[nf] = fq[1]; fz[nf] = fq[2];
        }
    }
    const float sgn = (ln & 1) ? 1.0f : -1.0f;
    const float qs  = (sec == 0) ? 0.125f * 1.4426950408889634f : 1.0f;

    #pragma unroll
    for (int mf = 0; mf < 4; ++mf) {
        #pragma unroll
        for (int r = 0; r < 4; ++r) {
            const int m = m0 + wrow*64 + mf*16 + g*4 + r;
            const int b = m >> 11, t = m & 2047;
            if (sec == 2) {
                #pragma unroll
                for (int nf = 0; nf < 4; ++nf)
                    dst[((size_t)(b*NH + hh[nf])*NT + t)*ND + dd[nf]] =
                        (_Float16)(acc[mf][nf][r] + cb[nf]);
            } else {
                const float px = pos[(size_t)m*3 + 0];
                const float py = pos[(size_t)m*3 + 1];
                const float pz = pos[(size_t)m*3 + 2];
                #pragma unroll
                for (int nf = 0; nf < 4; ++nf) {
                    const float x  = acc[mf][nf][r] + cb[nf];
                    const float xo = __shfl_xor(x, 1);
                    const float ang = px*fx[nf] + py*fy[nf] + pz*fz[nf];
                    float sn, cs;
                    __sincosf(ang, &sn, &cs);
                    const float out = (x*cs + sgn*xo*sn) * qs;
                    dst[((size_t)(b*NH + hh[nf])*NT + t)*ND + dd[nf]] = (_Float16)out;
                }
            }
        }
    }
}

// ============================================================================
// Kernel 2: fp16 flash attention on 32x32x16 MFMA (HK-style swapped QK^T).
// Wave owns 32 q-rows (q = lane&31 is lane-local for S, softmax, and PV-A).
// P stays in registers: cvt_pkrtz pairs + shfl_xor(32) half-wave exchange.
// exp2 domain (Q pre-scaled by log2e/8), defer-max THR=8 (T13).
// K/V in LDS with 68-elem row stride (all accesses at bank-conflict floor).
// LDS = 17.4 KB.  Grid (64 bh, 16 qt), 4 waves/block.
// ============================================================================
__global__ __launch_bounds__(256)
void attn_mfma_kernel(const _Float16* __restrict__ Qg, const _Float16* __restrict__ Kg,
                      const _Float16* __restrict__ Vg, _Float16* __restrict__ Og)
{
    __shared__ _Float16 Ks[64][68];      // [key][d]
    __shared__ _Float16 VsT[64][68];     // [d][key]

    const int tid  = threadIdx.x;
    const int wid  = tid >> 6;
    const int lane = tid & 63;
    const int m31  = lane & 31;
    const int hi   = lane >> 5;
    const int bh   = blockIdx.x;
    const int qt   = blockIdx.y;
    const int b = bh >> 4, h = bh & 15;
    const _Float16* Qp = Qg + (size_t)bh * NT * ND;
    const _Float16* Kp = Kg + (size_t)bh * NT * ND;
    const _Float16* Vp = Vg + (size_t)bh * NT * ND;

    const int qrow_g = qt*128 + wid*32 + m31;   // this lane's q row

    // Q B-frags: qfr[c] = Q[q][16c + 8hi .. +7]  (pre-scaled by log2e/8)
    half8 qfr[4];
    #pragma unroll
    for (int c = 0; c < 4; ++c)
        qfr[c] = *(const half8*)(Qp + (size_t)qrow_g*ND + 16*c + 8*hi);

    f32x16 o[2];
    #pragma unroll
    for (int e = 0; e < 16; ++e) { o[0][e] = 0.f; o[1][e] = 0.f; }
    float m_i = -INFINITY, l_i = 0.0f;

    // staging geometry (stride-68 rows)
    const int sr  = tid >> 2;            // K: key row 0..63
    const int sc0 = (tid & 3) * 16;      // K: d col base
    const int dp  = tid & 31;            // V: dword index (d = 2dp, 2dp+1)
    const int wv  = tid >> 5;            // V: key group 0..7
    const _Float16* kbase = Kp + (size_t)sr*ND + sc0;
    const _Float16* vbase = Vp + (size_t)(wv*8)*ND + 2*dp;

    half8 kv0 = *(const half8*)(kbase);
    half8 kv1 = *(const half8*)(kbase + 8);
    unsigned int vr[8];
    #pragma unroll
    for (int j = 0; j < 8; ++j)
        vr[j] = *(const unsigned int*)(vbase + (size_t)j*ND);

    for (int kt = 0; kt < NT; kt += 64) {
        if (kt) __syncthreads();
        *(half8*)&Ks[sr][sc0]     = kv0;
        *(half8*)&Ks[sr][sc0 + 8] = kv1;
        {
            ushort8v lo, hiw;
            #pragma unroll
            for (int j = 0; j < 8; ++j) {
                lo[j]  = (unsigned short)(vr[j] & 0xffffu);
                hiw[j] = (unsigned short)(vr[j] >> 16);
            }
            *(ushort8v*)&VsT[2*dp][wv*8]     = lo;
            *(ushort8v*)&VsT[2*dp + 1][wv*8] = hiw;
        }
        __syncthreads();

        // prefetch next K/V tile into regs (hides under compute)
        const int kn = kt + 64;
        if (kn < NT) {
            kv0 = *(const half8*)(kbase + (size_t)kn*ND);
            kv1 = *(const half8*)(kbase + (size_t)kn*ND + 8);
            #pragma unroll
            for (int j = 0; j < 8; ++j)
                vr[j] = *(const unsigned int*)(vbase + (size_t)(kn + j)*ND);
        }

        // ---- S^T = K . Q^T : st[kb] covers keys kb*32.. , q = m31 ----
        f32x16 st[2];
        #pragma unroll
        for (int e = 0; e < 16; ++e) { st[0][e] = 0.f; st[1][e] = 0.f; }

        __builtin_amdgcn_s_setprio(1);
        #pragma unroll
        for (int kb = 0; kb < 2; ++kb)
            #pragma unroll
            for (int c = 0; c < 4; ++c) {
                half8 kf = *(const half8*)&Ks[kb*32 + m31][16*c + 8*hi];
                st[kb] = MFMA32(kf, qfr[c], st[kb]);
            }
        __builtin_amdgcn_s_setprio(0);

        // ---- row max (lane holds 32 of 64 p-values for its q) ----
        float pmax = st[0][0];
        #pragma unroll
        for (int e = 1; e < 16; ++e) pmax = fmaxf(pmax, st[0][e]);
        #pragma unroll
        for (int e = 0; e < 16; ++e) pmax = fmaxf(pmax, st[1][e]);
        pmax = fmaxf(pmax, __shfl_xor(pmax, 32));

        // ---- defer-max: rescale only when max grew by > 8 (exp2 domain) ----
        if (!__all(pmax - m_i <= 8.0f)) {
            const float mnew  = fmaxf(m_i, pmax);
            const float alpha = fast_exp2(m_i - mnew);
            m_i = mnew;
            l_i *= alpha;
            #pragma unroll
            for (int reg = 0; reg < 16; ++reg) {
                const int qr = (reg & 3) + 8*(reg >> 2) + 4*hi;
                const float a = __shfl(alpha, qr);
                o[0][reg] *= a;
                o[1][reg] *= a;
            }
        }

        // ---- p = exp2(s - m), packed fp16 pairs; row sum ----
        float rs = 0.0f;
        unsigned int pku[2][8];
        #pragma unroll
        for (int kb = 0; kb < 2; ++kb)
            #pragma unroll
            for (int j = 0; j < 8; ++j) {
                const float p0 = fast_exp2(st[kb][2*j]     - m_i);
                const float p1 = fast_exp2(st[kb][2*j + 1] - m_i);
                rs += p0 + p1;
                pku[kb][j] = __builtin_bit_cast(unsigned int,
                               __builtin_amdgcn_cvt_pkrtz(p0, p1));
            }
        rs += __shfl_xor(rs, 32);
        l_i += rs;

        // ---- O += P . V : assemble pa per k-chain via half-wave exchange ----
        #pragma unroll
        for (int kc = 0; kc < 4; ++kc) {
            const int kb = kc >> 1;
            const unsigned int a0 = pku[kb][4*(kc & 1) + 0];
            const unsigned int a1 = pku[kb][4*(kc & 1) + 1];
            const unsigned int b0 = pku[kb][4*(kc & 1) + 2];
            const unsigned int b1 = pku[kb][4*(kc & 1) + 3];
            const unsigned int own0 = hi ? b0 : a0;
            const unsigned int own1 = hi ? b1 : a1;
            const unsigned int ex0  = hi ? a0 : b0;
            const unsigned int ex1  = hi ? a1 : b1;
            const unsigned int rc0 = __shfl_xor((int)ex0, 32);
            const unsigned int rc1 = __shfl_xor((int)ex1, 32);
            uint4v u;
            u.x = hi ? rc0 : own0;
            u.y = hi ? rc1 : own1;
            u.z = hi ? own0 : rc0;
            u.w = hi ? own1 : rc1;
            const half8 pa = __builtin_bit_cast(half8, u);
            const half8 vb0 = *(const half8*)&VsT[m31][16*kc + 8*hi];
            const half8 vb1 = *(const half8*)&VsT[32 + m31][16*kc + 8*hi];
            __builtin_amdgcn_s_setprio(1);
            o[0] = MFMA32(pa, vb0, o[0]);
            o[1] = MFMA32(pa, vb1, o[1]);
            __builtin_amdgcn_s_setprio(0);
        }
        __syncthreads();
    }

    // ---- epilogue: normalize (l redistributed to o-row layout), write ----
    #pragma unroll
    for (int reg = 0; reg < 16; ++reg) {
        const int qr = (reg & 3) + 8*(reg >> 2) + 4*hi;
        const float lq  = __shfl(l_i, qr);
        const float inv = 1.0f / lq;
        const int qg = qt*128 + wid*32 + qr;
        _Float16* dstp = Og + ((size_t)b*NT + qg)*NE + h*ND;
        dstp[m31]      = (_Float16)(o[0][reg] * inv);
        dstp[32 + m31] = (_Float16)(o[1][reg] * inv);
    }
}

// ============================================================================
// Kernel 3: fp16 MFMA out-projection: out(f32) = Oh * Woh^T + bias.
// ============================================================================
__global__ __launch_bounds__(256)
void out_proj_mfma_kernel(const _Float16* __restrict__ Ah,
                          const _Float16* __restrict__ Bh,
                          const float* __restrict__ bias,
                          float* __restrict__ out)
{
    __shared__ _Float16 Ash[128*32];
    __shared__ _Float16 Bsh[128*32];

    const int tid = threadIdx.x;
    const int wid = tid >> 6, lane = tid & 63;
    const int ln = lane & 15, g = lane >> 4;
    const int wrow = wid >> 1, wcol = wid & 1;
    const int m0 = blockIdx.x * 128, n0 = blockIdx.y * 128;

    const int r0 = tid >> 2, s0 = tid & 3;
    const int k8 = s0 ^ ((r0 >> 1) & 3);
    const _Float16* gA0 = Ah + (size_t)(m0 + r0)      * NE + k8*8;
    const _Float16* gA1 = Ah + (size_t)(m0 + r0 + 64) * NE + k8*8;
    const _Float16* gB0 = Bh + (size_t)(n0 + r0)      * NE + k8*8;
    const _Float16* gB1 = Bh + (size_t)(n0 + r0 + 64) * NE + k8*8;
    const int xr = g ^ ((ln >> 1) & 3);

    f32x4 acc[4][4];
    #pragma unroll
    for (int i = 0; i < 4; ++i)
        #pragma unroll
        for (int j = 0; j < 4; ++j) acc[i][j] = (f32x4){0.f,0.f,0.f,0.f};

    half8 va0 = *(const half8*)gA0;
    half8 va1 = *(const half8*)gA1;
    half8 vb0 = *(const half8*)gB0;
    half8 vb1 = *(const half8*)gB1;

    for (int kt = 0; kt < NE; kt += 32) {
        if (kt) __syncthreads();
        *(half8*)&Ash[tid*8]       = va0;
        *(half8*)&Ash[(tid+256)*8] = va1;
        *(half8*)&Bsh[tid*8]       = vb0;
        *(half8*)&Bsh[(tid+256)*8] = vb1;
        __syncthreads();
        const int kn = kt + 32;
        if (kn < NE) {
            va0 = *(const half8*)(gA0 + kn);
            va1 = *(const half8*)(gA1 + kn);
            vb0 = *(const half8*)(gB0 + kn);
            vb1 = *(const half8*)(gB1 + kn);
        }
        half8 af[4], bf[4];
        #pragma unroll
        for (int mf = 0; mf < 4; ++mf)
            af[mf] = *(const half8*)&Ash[(wrow*64 + mf*16 + ln)*32 + xr*8];
        #pragma unroll
        for (int nf = 0; nf < 4; ++nf)
            bf[nf] = *(const half8*)&Bsh[(wcol*64 + nf*16 + ln)*32 + xr*8];
        __builtin_amdgcn_s_setprio(1);
        #pragma unroll
        for (int mf = 0; mf < 4; ++mf)
            #pragma unroll
            for (int nf = 0; nf < 4; ++nf)
                acc[mf][nf] = MFMA16(af[mf], bf[nf], acc[mf][nf]);
        __builtin_amdgcn_s_setprio(0);
    }

    float cb[4];
    #pragma unroll
    for (int nf = 0; nf < 4; ++nf) cb[nf] = bias[n0 + wcol*64 + nf*16 + ln];

    #pragma unroll
    for (int mf = 0; mf < 4; ++mf)
        #pragma unroll
        for (int r = 0; r < 4; ++r) {
            const int m = m0 + wrow*64 + mf*16 + g*4 + r;
            #pragma unroll
            for (int nf = 0; nf < 4; ++nf)
                out[(size_t)m*NE + n0 + wcol*64 + nf*16 + ln] = acc[mf][nf][r] + cb[nf];
        }
}

extern "C" void kernel_launch(void* const* d_in, const int* in_sizes, int n_in,
                              void* d_out, int out_size, void* d_ws, size_t ws_size,
                              hipStream_t stream)
{
    const float* X   = (const float*)d_in[0];
    const float* pos = (const float*)d_in[1];
    const float* Wi  = (const float*)d_in[2];
    const float* bi  = (const float*)d_in[3];
    const float* Wo  = (const float*)d_in[4];
    const float* bo  = (const float*)d_in[5];
    const float* fr  = (const float*)d_in[6];
    float* out = (float*)d_out;

    _Float16* Xh  = (_Float16*)d_ws;            // 8388608
    _Float16* Wih = Xh  + 8388608;              // 3145728
    _Float16* Woh = Wih + 3145728;              // 1048576
    _Float16* Qh  = Woh + 1048576;              // 8388608
    _Float16* Kh  = Qh  + 8388608;
    _Float16* Vh  = Kh  + 8388608;
    _Float16* Oh  = Vh  + 8388608;

    cvt_kernel          <<<3072, 256, 0, stream>>>(X, Wi, Wo, Xh, Wih, Woh);
    qkv_mfma_kernel     <<<dim3(64, 24), 256, 0, stream>>>(Xh, Wih, bi, pos, fr, Qh, Kh, Vh);
    attn_mfma_kernel    <<<dim3(64, 16), 256, 0, stream>>>(Qh, Kh, Vh, Oh);
    out_proj_mfma_kernel<<<dim3(64, 8),  256, 0, stream>>>(Oh, Woh, bo, out);
}

// Round 6
// 242.531 us; speedup vs baseline: 8.2315x; 1.0348x over previous
//
#include <hip/hip_runtime.h>
#include <math.h>

#define NB 4
#define NT 2048
#define NE 1024
#define NH 16
#define ND 64
#define NF 32

typedef _Float16 half8 __attribute__((ext_vector_type(8)));
typedef _Float16 half4 __attribute__((ext_vector_type(4)));
typedef unsigned int uint2v __attribute__((ext_vector_type(2)));
typedef unsigned int uint4v __attribute__((ext_vector_type(4)));
typedef float f32x4 __attribute__((ext_vector_type(4)));
typedef float f32x16 __attribute__((ext_vector_type(16)));
#define MFMA16(a, b, c) __builtin_amdgcn_mfma_f32_16x16x32_f16(a, b, c, 0, 0, 0)
#define MFMA32(a, b, c) __builtin_amdgcn_mfma_f32_32x32x16_f16(a, b, c, 0, 0, 0)

__device__ __forceinline__ float fast_exp2(float x) {
    float r;
    asm volatile("v_exp_f32 %0, %1" : "=v"(r) : "v"(x));
    return r;
}
__device__ __forceinline__ float max3f(float a, float b, float c) {
    return fmaxf(fmaxf(a, b), c);
}

// ============================================================================
// Kernel 0: fp32 -> fp16 conversion of X, Wi, Wo (one pass, grid-stride).
// ============================================================================
__global__ __launch_bounds__(256)
void cvt_kernel(const float* __restrict__ X, const float* __restrict__ Wi,
                const float* __restrict__ Wo,
                _Float16* __restrict__ Xh, _Float16* __restrict__ Wih,
                _Float16* __restrict__ Woh)
{
    const size_t NX = (size_t)8388608, NWI = 3145728, NWO = 1048576;
    const size_t TOT = (NX + NWI + NWO) / 8;   // half8 groups
    for (size_t gidx = (size_t)blockIdx.x*256 + threadIdx.x; gidx < TOT;
         gidx += (size_t)gridDim.x*256) {
        size_t i = gidx*8;
        const float* src; _Float16* dst; size_t off;
        if (i < NX)            { src = X;  dst = Xh;  off = i; }
        else if (i < NX + NWI) { src = Wi; dst = Wih; off = i - NX; }
        else                   { src = Wo; dst = Woh; off = i - NX - NWI; }
        float4 a = *(const float4*)(src + off);
        float4 b = *(const float4*)(src + off + 4);
        half8 h;
        h[0]=(_Float16)a.x; h[1]=(_Float16)a.y; h[2]=(_Float16)a.z; h[3]=(_Float16)a.w;
        h[4]=(_Float16)b.x; h[5]=(_Float16)b.y; h[6]=(_Float16)b.z; h[7]=(_Float16)b.w;
        *(half8*)(dst + off) = h;
    }
}

// ============================================================================
// Kernel 1: fp16 MFMA GEMM  C = Xh * Wih^T (+bias), fused rotary epilogue.
// Q additionally scaled by (1/8)*log2(e) so attention runs in exp2 domain.
// ============================================================================
__global__ __launch_bounds__(256)
void qkv_mfma_kernel(const _Float16* __restrict__ Ah,
                     const _Float16* __restrict__ Bh,
                     const float* __restrict__ bias,
                     const float* __restrict__ pos,
                     const float* __restrict__ freqs,
                     _Float16* __restrict__ Qh,
                     _Float16* __restrict__ Kh,
                     _Float16* __restrict__ Vh)
{
    __shared__ _Float16 Ash[128*32];
    __shared__ _Float16 Bsh[128*32];

    const int tid = threadIdx.x;
    const int wid = tid >> 6, lane = tid & 63;
    const int ln = lane & 15, g = lane >> 4;
    const int wrow = wid >> 1, wcol = wid & 1;
    const int m0 = blockIdx.x * 128, n0 = blockIdx.y * 128;

    const int r0 = tid >> 2, s0 = tid & 3;
    const int k8 = s0 ^ ((r0 >> 1) & 3);
    const _Float16* gA0 = Ah + (size_t)(m0 + r0)      * NE + k8*8;
    const _Float16* gA1 = Ah + (size_t)(m0 + r0 + 64) * NE + k8*8;
    const _Float16* gB0 = Bh + (size_t)(n0 + r0)      * NE + k8*8;
    const _Float16* gB1 = Bh + (size_t)(n0 + r0 + 64) * NE + k8*8;

    const int xr = g ^ ((ln >> 1) & 3);

    f32x4 acc[4][4];
    #pragma unroll
    for (int i = 0; i < 4; ++i)
        #pragma unroll
        for (int j = 0; j < 4; ++j) acc[i][j] = (f32x4){0.f,0.f,0.f,0.f};

    half8 va0 = *(const half8*)gA0;
    half8 va1 = *(const half8*)gA1;
    half8 vb0 = *(const half8*)gB0;
    half8 vb1 = *(const half8*)gB1;

    for (int kt = 0; kt < NE; kt += 32) {
        if (kt) __syncthreads();
        *(half8*)&Ash[tid*8]       = va0;
        *(half8*)&Ash[(tid+256)*8] = va1;
        *(half8*)&Bsh[tid*8]       = vb0;
        *(half8*)&Bsh[(tid+256)*8] = vb1;
        __syncthreads();
        const int kn = kt + 32;
        if (kn < NE) {
            va0 = *(const half8*)(gA0 + kn);
            va1 = *(const half8*)(gA1 + kn);
            vb0 = *(const half8*)(gB0 + kn);
            vb1 = *(const half8*)(gB1 + kn);
        }
        half8 af[4], bf[4];
        #pragma unroll
        for (int mf = 0; mf < 4; ++mf)
            af[mf] = *(const half8*)&Ash[(wrow*64 + mf*16 + ln)*32 + xr*8];
        #pragma unroll
        for (int nf = 0; nf < 4; ++nf)
            bf[nf] = *(const half8*)&Bsh[(wcol*64 + nf*16 + ln)*32 + xr*8];
        __builtin_amdgcn_s_setprio(1);
        #pragma unroll
        for (int mf = 0; mf < 4; ++mf)
            #pragma unroll
            for (int nf = 0; nf < 4; ++nf)
                acc[mf][nf] = MFMA16(af[mf], bf[nf], acc[mf][nf]);
        __builtin_amdgcn_s_setprio(0);
    }

    const int sec = n0 >> 10;
    _Float16* dst = (sec == 0) ? Qh : (sec == 1) ? Kh : Vh;

    float cb[4], fx[4], fy[4], fz[4];
    int hh[4], dd[4];
    #pragma unroll
    for (int nf = 0; nf < 4; ++nf) {
        const int col = n0 + wcol*64 + nf*16 + ln;
        cb[nf] = bias[col];
        const int e = col & 1023;
        hh[nf] = e >> 6; dd[nf] = e & 63;
        if (sec != 2) {
            const float* fq = freqs + ((size_t)hh[nf]*NF + (dd[nf] >> 1))*3;
            fx[nf] = fq[0]; fy[nf] = fq[1]; fz[nf] = fq[2];
        }
    }
    const float sgn = (ln & 1) ? 1.0f : -1.0f;
    const float qs  = (sec == 0) ? 0.125f * 1.4426950408889634f : 1.0f;

    #pragma unroll
    for (int mf = 0; mf < 4; ++mf) {
        #pragma unroll
        for (int r = 0; r < 4; ++r) {
            const int m = m0 + wrow*64 + mf*16 + g*4 + r;
            const int b = m >> 11, t = m & 2047;
            if (sec == 2) {
                #pragma unroll
                for (int nf = 0; nf < 4; ++nf)
                    dst[((size_t)(b*NH + hh[nf])*NT + t)*ND + dd[nf]] =
                        (_Float16)(acc[mf][nf][r] + cb[nf]);
            } else {
                const float px = pos[(size_t)m*3 + 0];
                const float py = pos[(size_t)m*3 + 1];
                const float pz = pos[(size_t)m*3 + 2];
                #pragma unroll
                for (int nf = 0; nf < 4; ++nf) {
                    const float x  = acc[mf][nf][r] + cb[nf];
                    const float xo = __shfl_xor(x, 1);
                    const float ang = px*fx[nf] + py*fy[nf] + pz*fz[nf];
                    float sn, cs;
                    __sincosf(ang, &sn, &cs);
                    const float out = (x*cs + sgn*xo*sn) * qs;
                    dst[((size_t)(b*NH + hh[nf])*NT + t)*ND + dd[nf]] = (_Float16)out;
                }
            }
        }
    }
}

// ============================================================================
// Kernel 2: fp16 flash attention, 32x32x16 MFMA, swapped QK^T (q lane-local).
// R6: LDS double-buffer with ONE barrier per KV tile; QK accumulator
// initialized to -m (kills 32 subs/tile); m_init=8 so defer-max never fires
// on typical data (branch kept for safety); permlane32_swap P-exchange;
// v_perm V unpack; max3/sum trees. P in registers throughout.
// ============================================================================
__global__ __launch_bounds__(256)
void attn_mfma_kernel(const _Float16* __restrict__ Qg, const _Float16* __restrict__ Kg,
                      const _Float16* __restrict__ Vg, _Float16* __restrict__ Og)
{
    __shared__ _Float16 Ks[2][64][68];      // [buf][key][d]
    __shared__ _Float16 VsT[2][64][68];     // [buf][d][key]

    const int tid  = threadIdx.x;
    const int wid  = tid >> 6;
    const int lane = tid & 63;
    const int m31  = lane & 31;
    const int hi   = lane >> 5;
    const int bh   = blockIdx.x;
    const int qt   = blockIdx.y;
    const int b = bh >> 4, h = bh & 15;
    const _Float16* Qp = Qg + (size_t)bh * NT * ND;
    const _Float16* Kp = Kg + (size_t)bh * NT * ND;
    const _Float16* Vp = Vg + (size_t)bh * NT * ND;

    const int qrow_g = qt*128 + wid*32 + m31;

    half8 qfr[4];
    #pragma unroll
    for (int c = 0; c < 4; ++c)
        qfr[c] = *(const half8*)(Qp + (size_t)qrow_g*ND + 16*c + 8*hi);

    f32x16 o0, o1;
    #pragma unroll
    for (int e = 0; e < 16; ++e) { o0[e] = 0.f; o1[e] = 0.f; }
    float m_i = 8.0f, l_i = 0.0f;    // static max guess; defer-max guards it

    // staging geometry
    const int sr  = tid >> 2;            // K: key row 0..63
    const int sc0 = (tid & 3) * 16;      // K: d col base
    const int dp  = tid & 31;            // V: dword index (d = 2dp, 2dp+1)
    const int wv  = tid >> 5;            // V: key group 0..7
    const _Float16* kbase = Kp + (size_t)sr*ND + sc0;
    const _Float16* vbase = Vp + (size_t)(wv*8)*ND + 2*dp;

    half8 kv0, kv1;
    unsigned int vr[8];

    #define LOADREGS(off)  do {                                              \
        kv0 = *(const half8*)(kbase + (size_t)(off)*ND);                     \
        kv1 = *(const half8*)(kbase + (size_t)(off)*ND + 8);                 \
        _Pragma("unroll")                                                    \
        for (int j = 0; j < 8; ++j)                                          \
            vr[j] = *(const unsigned int*)(vbase + (size_t)((off) + j)*ND);  \
    } while (0)

    #define STOREBUF(bf)  do {                                               \
        *(half8*)&Ks[bf][sr][sc0]     = kv0;                                 \
        *(half8*)&Ks[bf][sr][sc0 + 8] = kv1;                                 \
        uint4v lod, hid;                                                     \
        _Pragma("unroll")                                                    \
        for (int j2 = 0; j2 < 4; ++j2) {                                     \
            lod[j2] = __builtin_amdgcn_perm(vr[2*j2+1], vr[2*j2], 0x05040100u); \
            hid[j2] = __builtin_amdgcn_perm(vr[2*j2+1], vr[2*j2], 0x07060302u); \
        }                                                                    \
        *(uint4v*)&VsT[bf][2*dp][wv*8]     = lod;                            \
        *(uint4v*)&VsT[bf][2*dp + 1][wv*8] = hid;                            \
    } while (0)

    LOADREGS(0);
    STOREBUF(0);
    LOADREGS(64);

    for (int t = 0; t < 32; ++t) {
        const int cur = t & 1;
        __syncthreads();
        if (t < 31) STOREBUF(cur ^ 1);          // regs hold tile t+1
        if (t < 30) LOADREGS((t + 2) * 64);     // prefetch tile t+2

        // ---- S' = K.Q^T - m  (C initialized to -m_i) ----
        f32x16 st0, st1;
        const float mneg = -m_i;
        #pragma unroll
        for (int e = 0; e < 16; ++e) { st0[e] = mneg; st1[e] = mneg; }

        __builtin_amdgcn_s_setprio(1);
        #pragma unroll
        for (int c = 0; c < 4; ++c) {
            half8 kf0 = *(const half8*)&Ks[cur][m31][16*c + 8*hi];
            half8 kf1 = *(const half8*)&Ks[cur][32 + m31][16*c + 8*hi];
            st0 = MFMA32(kf0, qfr[c], st0);
            st1 = MFMA32(kf1, qfr[c], st1);
        }
        __builtin_amdgcn_s_setprio(0);

        // ---- row max over 32 regs (tree) + half-wave combine ----
        float t0 = max3f(st0[0],  st0[1],  st0[2]);
        float t1 = max3f(st0[3],  st0[4],  st0[5]);
        float t2 = max3f(st0[6],  st0[7],  st0[8]);
        float t3 = max3f(st0[9],  st0[10], st0[11]);
        float t4 = max3f(st0[12], st0[13], st0[14]);
        float t5 = max3f(st0[15], st1[0],  st1[1]);
        float t6 = max3f(st1[2],  st1[3],  st1[4]);
        float t7 = max3f(st1[5],  st1[6],  st1[7]);
        float t8 = max3f(st1[8],  st1[9],  st1[10]);
        float t9 = max3f(st1[11], st1[12], st1[13]);
        float ta = fmaxf(st1[14], st1[15]);
        float u0 = max3f(t0, t1, t2);
        float u1 = max3f(t3, t4, t5);
        float u2 = max3f(t6, t7, t8);
        float u3 = fmaxf(t9, ta);
        float pmax = fmaxf(max3f(u0, u1, u2), u3);
        pmax = fmaxf(pmax, __shfl_xor(pmax, 32));

        // ---- defer-max: rescale only if max exceeded the running bound ----
        if (!__all(pmax <= 8.0f)) {
            const float delta = (pmax > 8.0f) ? pmax : 0.0f;
            const float alpha = fast_exp2(-delta);
            m_i += delta;
            l_i *= alpha;
            #pragma unroll
            for (int reg = 0; reg < 16; ++reg) {
                const int qr = (reg & 3) + 8*(reg >> 2) + 4*hi;
                const float a = __shfl(alpha, qr);
                o0[reg] *= a; o1[reg] *= a;
            }
            #pragma unroll
            for (int e = 0; e < 16; ++e) { st0[e] -= delta; st1[e] -= delta; }
        }

        // ---- p = exp2(s'), packed fp16; 4-chain sum ----
        float r0 = 0.f, r1 = 0.f, r2 = 0.f, r3 = 0.f;
        unsigned int pku0[8], pku1[8];
        #pragma unroll
        for (int j = 0; j < 8; ++j) {
            const float pa0 = fast_exp2(st0[2*j]);
            const float pa1 = fast_exp2(st0[2*j + 1]);
            const float pb0 = fast_exp2(st1[2*j]);
            const float pb1 = fast_exp2(st1[2*j + 1]);
            if ((j & 1) == 0) { r0 += pa0 + pa1; r1 += pb0 + pb1; }
            else              { r2 += pa0 + pa1; r3 += pb0 + pb1; }
            pku0[j] = __builtin_bit_cast(unsigned int, __builtin_amdgcn_cvt_pkrtz(pa0, pa1));
            pku1[j] = __builtin_bit_cast(unsigned int, __builtin_amdgcn_cvt_pkrtz(pb0, pb1));
        }
        float rs = (r0 + r1) + (r2 + r3);
        rs += __shfl_xor(rs, 32);
        l_i += rs;

        // ---- O += P . V : permlane32_swap assembles the A-frag ----
        #pragma unroll
        for (int kc = 0; kc < 4; ++kc) {
            const unsigned int a0 = (kc < 2) ? pku0[4*(kc & 1) + 0] : pku1[4*(kc & 1) + 0];
            const unsigned int a1 = (kc < 2) ? pku0[4*(kc & 1) + 1] : pku1[4*(kc & 1) + 1];
            const unsigned int b0 = (kc < 2) ? pku0[4*(kc & 1) + 2] : pku1[4*(kc & 1) + 2];
            const unsigned int b1 = (kc < 2) ? pku0[4*(kc & 1) + 3] : pku1[4*(kc & 1) + 3];
            uint2v rpa = __builtin_amdgcn_permlane32_swap(a0, b0, false, false);
            uint2v rpb = __builtin_amdgcn_permlane32_swap(a1, b1, false, false);
            uint4v u;
            u[0] = rpa[0]; u[1] = rpb[0]; u[2] = rpa[1]; u[3] = rpb[1];
            const half8 pa = __builtin_bit_cast(half8, u);
            const half8 vb0 = *(const half8*)&VsT[cur][m31][16*kc + 8*hi];
            const half8 vb1 = *(const half8*)&VsT[cur][32 + m31][16*kc + 8*hi];
            __builtin_amdgcn_s_setprio(1);
            o0 = MFMA32(pa, vb0, o0);
            o1 = MFMA32(pa, vb1, o1);
            __builtin_amdgcn_s_setprio(0);
        }
    }

    // ---- epilogue: normalize (l redistributed to o-row layout), write ----
    #pragma unroll
    for (int reg = 0; reg < 16; ++reg) {
        const int qr = (reg & 3) + 8*(reg >> 2) + 4*hi;
        const float lq  = __shfl(l_i, qr);
        const float inv = 1.0f / lq;
        const int qg = qt*128 + wid*32 + qr;
        _Float16* dstp = Og + ((size_t)b*NT + qg)*NE + h*ND;
        dstp[m31]      = (_Float16)(o0[reg] * inv);
        dstp[32 + m31] = (_Float16)(o1[reg] * inv);
    }
    #undef LOADREGS
    #undef STOREBUF
}

// ============================================================================
// Kernel 3: fp16 MFMA out-projection: out(f32) = Oh * Woh^T + bias.
// ============================================================================
__global__ __launch_bounds__(256)
void out_proj_mfma_kernel(const _Float16* __restrict__ Ah,
                          const _Float16* __restrict__ Bh,
                          const float* __restrict__ bias,
                          float* __restrict__ out)
{
    __shared__ _Float16 Ash[128*32];
    __shared__ _Float16 Bsh[128*32];

    const int tid = threadIdx.x;
    const int wid = tid >> 6, lane = tid & 63;
    const int ln = lane & 15, g = lane >> 4;
    const int wrow = wid >> 1, wcol = wid & 1;
    const int m0 = blockIdx.x * 128, n0 = blockIdx.y * 128;

    const int r0 = tid >> 2, s0 = tid & 3;
    const int k8 = s0 ^ ((r0 >> 1) & 3);
    const _Float16* gA0 = Ah + (size_t)(m0 + r0)      * NE + k8*8;
    const _Float16* gA1 = Ah + (size_t)(m0 + r0 + 64) * NE + k8*8;
    const _Float16* gB0 = Bh + (size_t)(n0 + r0)      * NE + k8*8;
    const _Float16* gB1 = Bh + (size_t)(n0 + r0 + 64) * NE + k8*8;
    const int xr = g ^ ((ln >> 1) & 3);

    f32x4 acc[4][4];
    #pragma unroll
    for (int i = 0; i < 4; ++i)
        #pragma unroll
        for (int j = 0; j < 4; ++j) acc[i][j] = (f32x4){0.f,0.f,0.f,0.f};

    half8 va0 = *(const half8*)gA0;
    half8 va1 = *(const half8*)gA1;
    half8 vb0 = *(const half8*)gB0;
    half8 vb1 = *(const half8*)gB1;

    for (int kt = 0; kt < NE; kt += 32) {
        if (kt) __syncthreads();
        *(half8*)&Ash[tid*8]       = va0;
        *(half8*)&Ash[(tid+256)*8] = va1;
        *(half8*)&Bsh[tid*8]       = vb0;
        *(half8*)&Bsh[(tid+256)*8] = vb1;
        __syncthreads();
        const int kn = kt + 32;
        if (kn < NE) {
            va0 = *(const half8*)(gA0 + kn);
            va1 = *(const half8*)(gA1 + kn);
            vb0 = *(const half8*)(gB0 + kn);
            vb1 = *(const half8*)(gB1 + kn);
        }
        half8 af[4], bf[4];
        #pragma unroll
        for (int mf = 0; mf < 4; ++mf)
            af[mf] = *(const half8*)&Ash[(wrow*64 + mf*16 + ln)*32 + xr*8];
        #pragma unroll
        for (int nf = 0; nf < 4; ++nf)
            bf[nf] = *(const half8*)&Bsh[(wcol*64 + nf*16 + ln)*32 + xr*8];
        __builtin_amdgcn_s_setprio(1);
        #pragma unroll
        for (int mf = 0; mf < 4; ++mf)
            #pragma unroll
            for (int nf = 0; nf < 4; ++nf)
                acc[mf][nf] = MFMA16(af[mf], bf[nf], acc[mf][nf]);
        __builtin_amdgcn_s_setprio(0);
    }

    float cb[4];
    #pragma unroll
    for (int nf = 0; nf < 4; ++nf) cb[nf] = bias[n0 + wcol*64 + nf*16 + ln];

    #pragma unroll
    for (int mf = 0; mf < 4; ++mf)
        #pragma unroll
        for (int r = 0; r < 4; ++r) {
            const int m = m0 + wrow*64 + mf*16 + g*4 + r;
            #pragma unroll
            for (int nf = 0; nf < 4; ++nf)
                out[(size_t)m*NE + n0 + wcol*64 + nf*16 + ln] = acc[mf][nf][r] + cb[nf];
        }
}

extern "C" void kernel_launch(void* const* d_in, const int* in_sizes, int n_in,
                              void* d_out, int out_size, void* d_ws, size_t ws_size,
                              hipStream_t stream)
{
    const float* X   = (const float*)d_in[0];
    const float* pos = (const float*)d_in[1];
    const float* Wi  = (const float*)d_in[2];
    const float* bi  = (const float*)d_in[3];
    const float* Wo  = (const float*)d_in[4];
    const float* bo  = (const float*)d_in[5];
    const float* fr  = (const float*)d_in[6];
    float* out = (float*)d_out;

    _Float16* Xh  = (_Float16*)d_ws;            // 8388608
    _Float16* Wih = Xh  + 8388608;              // 3145728
    _Float16* Woh = Wih + 3145728;              // 1048576
    _Float16* Qh  = Woh + 1048576;              // 8388608
    _Float16* Kh  = Qh  + 8388608;
    _Float16* Vh  = Kh  + 8388608;
    _Float16* Oh  = Vh  + 8388608;

    cvt_kernel          <<<3072, 256, 0, stream>>>(X, Wi, Wo, Xh, Wih, Woh);
    qkv_mfma_kernel     <<<dim3(64, 24), 256, 0, stream>>>(Xh, Wih, bi, pos, fr, Qh, Kh, Vh);
    attn_mfma_kernel    <<<dim3(64, 16), 256, 0, stream>>>(Qh, Kh, Vh, Oh);
    out_proj_mfma_kernel<<<dim3(64, 8),  256, 0, stream>>>(Oh, Woh, bo, out);
}

// Round 8
// 223.296 us; speedup vs baseline: 8.9405x; 1.0861x over previous
//
#include <hip/hip_runtime.h>
#include <math.h>

#define NB 4
#define NT 2048
#define NE 1024
#define NH 16
#define ND 64
#define NF 32

typedef _Float16 half8 __attribute__((ext_vector_type(8)));
typedef __fp16 fp16x2 __attribute__((ext_vector_type(2)));
typedef unsigned int uint2v __attribute__((ext_vector_type(2)));
typedef unsigned int uint4v __attribute__((ext_vector_type(4)));
typedef float f32x4 __attribute__((ext_vector_type(4)));
typedef float f32x16 __attribute__((ext_vector_type(16)));
#define MFMA16(a, b, c) __builtin_amdgcn_mfma_f32_16x16x32_f16(a, b, c, 0, 0, 0)
#define MFMA32(a, b, c) __builtin_amdgcn_mfma_f32_32x32x16_f16(a, b, c, 0, 0, 0)

__device__ __forceinline__ float fast_exp2(float x) {
    float r;
    asm volatile("v_exp_f32 %0, %1" : "=v"(r) : "v"(x));
    return r;
}
__device__ __forceinline__ float max3f(float a, float b, float c) {
    return fmaxf(fmaxf(a, b), c);
}

// ============================================================================
// Kernel 0: fp32 -> fp16 conversion of X, Wi, Wo (one pass, grid-stride).
// ============================================================================
__global__ __launch_bounds__(256)
void cvt_kernel(const float* __restrict__ X, const float* __restrict__ Wi,
                const float* __restrict__ Wo,
                _Float16* __restrict__ Xh, _Float16* __restrict__ Wih,
                _Float16* __restrict__ Woh)
{
    const size_t NX = (size_t)8388608, NWI = 3145728, NWO = 1048576;
    const size_t TOT = (NX + NWI + NWO) / 8;   // half8 groups
    for (size_t gidx = (size_t)blockIdx.x*256 + threadIdx.x; gidx < TOT;
         gidx += (size_t)gridDim.x*256) {
        size_t i = gidx*8;
        const float* src; _Float16* dst; size_t off;
        if (i < NX)            { src = X;  dst = Xh;  off = i; }
        else if (i < NX + NWI) { src = Wi; dst = Wih; off = i - NX; }
        else                   { src = Wo; dst = Woh; off = i - NX - NWI; }
        float4 a = *(const float4*)(src + off);
        float4 b = *(const float4*)(src + off + 4);
        half8 h;
        h[0]=(_Float16)a.x; h[1]=(_Float16)a.y; h[2]=(_Float16)a.z; h[3]=(_Float16)a.w;
        h[4]=(_Float16)b.x; h[5]=(_Float16)b.y; h[6]=(_Float16)b.z; h[7]=(_Float16)b.w;
        *(half8*)(dst + off) = h;
    }
}

// ============================================================================
// Kernel 1: fp16 MFMA GEMM  C = Xh * Wih^T (+bias), fused rotary epilogue.
// Q additionally scaled by (1/8)*log2(e) so attention runs in exp2 domain.
// ============================================================================
__global__ __launch_bounds__(256)
void qkv_mfma_kernel(const _Float16* __restrict__ Ah,
                     const _Float16* __restrict__ Bh,
                     const float* __restrict__ bias,
                     const float* __restrict__ pos,
                     const float* __restrict__ freqs,
                     _Float16* __restrict__ Qh,
                     _Float16* __restrict__ Kh,
                     _Float16* __restrict__ Vh)
{
    __shared__ _Float16 Ash[128*32];
    __shared__ _Float16 Bsh[128*32];

    const int tid = threadIdx.x;
    const int wid = tid >> 6, lane = tid & 63;
    const int ln = lane & 15, g = lane >> 4;
    const int wrow = wid >> 1, wcol = wid & 1;
    const int m0 = blockIdx.x * 128, n0 = blockIdx.y * 128;

    const int r0 = tid >> 2, s0 = tid & 3;
    const int k8 = s0 ^ ((r0 >> 1) & 3);
    const _Float16* gA0 = Ah + (size_t)(m0 + r0)      * NE + k8*8;
    const _Float16* gA1 = Ah + (size_t)(m0 + r0 + 64) * NE + k8*8;
    const _Float16* gB0 = Bh + (size_t)(n0 + r0)      * NE + k8*8;
    const _Float16* gB1 = Bh + (size_t)(n0 + r0 + 64) * NE + k8*8;

    const int xr = g ^ ((ln >> 1) & 3);

    f32x4 acc[4][4];
    #pragma unroll
    for (int i = 0; i < 4; ++i)
        #pragma unroll
        for (int j = 0; j < 4; ++j) acc[i][j] = (f32x4){0.f,0.f,0.f,0.f};

    half8 va0 = *(const half8*)gA0;
    half8 va1 = *(const half8*)gA1;
    half8 vb0 = *(const half8*)gB0;
    half8 vb1 = *(const half8*)gB1;

    for (int kt = 0; kt < NE; kt += 32) {
        if (kt) __syncthreads();
        *(half8*)&Ash[tid*8]       = va0;
        *(half8*)&Ash[(tid+256)*8] = va1;
        *(half8*)&Bsh[tid*8]       = vb0;
        *(half8*)&Bsh[(tid+256)*8] = vb1;
        __syncthreads();
        const int kn = kt + 32;
        if (kn < NE) {
            va0 = *(const half8*)(gA0 + kn);
            va1 = *(const half8*)(gA1 + kn);
            vb0 = *(const half8*)(gB0 + kn);
            vb1 = *(const half8*)(gB1 + kn);
        }
        half8 af[4], bf[4];
        #pragma unroll
        for (int mf = 0; mf < 4; ++mf)
            af[mf] = *(const half8*)&Ash[(wrow*64 + mf*16 + ln)*32 + xr*8];
        #pragma unroll
        for (int nf = 0; nf < 4; ++nf)
            bf[nf] = *(const half8*)&Bsh[(wcol*64 + nf*16 + ln)*32 + xr*8];
        __builtin_amdgcn_s_setprio(1);
        #pragma unroll
        for (int mf = 0; mf < 4; ++mf)
            #pragma unroll
            for (int nf = 0; nf < 4; ++nf)
                acc[mf][nf] = MFMA16(af[mf], bf[nf], acc[mf][nf]);
        __builtin_amdgcn_s_setprio(0);
    }

    const int sec = n0 >> 10;
    _Float16* dst = (sec == 0) ? Qh : (sec == 1) ? Kh : Vh;

    float cb[4], fx[4], fy[4], fz[4];
    int hh[4], dd[4];
    #pragma unroll
    for (int nf = 0; nf < 4; ++nf) {
        const int col = n0 + wcol*64 + nf*16 + ln;
        cb[nf] = bias[col];
        const int e = col & 1023;
        hh[nf] = e >> 6; dd[nf] = e & 63;
        if (sec != 2) {
            const float* fq = freqs + ((size_t)hh[nf]*NF + (dd[nf] >> 1))*3;
            fx[nf] = fq[0]; fy[nf] = fq[1]; fz[nf] = fq[2];
        }
    }
    const float sgn = (ln & 1) ? 1.0f : -1.0f;
    const float qs  = (sec == 0) ? 0.125f * 1.4426950408889634f : 1.0f;

    #pragma unroll
    for (int mf = 0; mf < 4; ++mf) {
        #pragma unroll
        for (int r = 0; r < 4; ++r) {
            const int m = m0 + wrow*64 + mf*16 + g*4 + r;
            const int b = m >> 11, t = m & 2047;
            if (sec == 2) {
                #pragma unroll
                for (int nf = 0; nf < 4; ++nf)
                    dst[((size_t)(b*NH + hh[nf])*NT + t)*ND + dd[nf]] =
                        (_Float16)(acc[mf][nf][r] + cb[nf]);
            } else {
                const float px = pos[(size_t)m*3 + 0];
                const float py = pos[(size_t)m*3 + 1];
                const float pz = pos[(size_t)m*3 + 2];
                #pragma unroll
                for (int nf = 0; nf < 4; ++nf) {
                    const float x  = acc[mf][nf][r] + cb[nf];
                    const float xo = __shfl_xor(x, 1);
                    const float ang = px*fx[nf] + py*fy[nf] + pz*fz[nf];
                    float sn, cs;
                    __sincosf(ang, &sn, &cs);
                    const float out = (x*cs + sgn*xo*sn) * qs;
                    dst[((size_t)(b*NH + hh[nf])*NT + t)*ND + dd[nf]] = (_Float16)out;
                }
            }
        }
    }
}

// ============================================================================
// Kernel 2: fp16 flash attention, 32x32x16 MFMA, swapped QK^T.
// R7b: 8 waves/block (512 thr, 256 q-rows), grid (64,8). exp2-first softmax:
// acc pre-init to -m, exp2 straight from MFMA, p-max via fused max3 during
// the exp loop, v_dot2_f32_f16 row sums on packed P. Rare exact slow path
// (rcp/log2) when any p > 1. Stride-70 LDS rows. One barrier per tile.
// ============================================================================
__global__ __launch_bounds__(512, 4)
void attn_mfma_kernel(const _Float16* __restrict__ Qg, const _Float16* __restrict__ Kg,
                      const _Float16* __restrict__ Vg, _Float16* __restrict__ Og)
{
    __shared__ _Float16 Ks[2][64][70];      // [buf][key][d]
    __shared__ _Float16 VsT[2][64][70];     // [buf][d][key]

    const int tid  = threadIdx.x;
    const int wid  = tid >> 6;
    const int lane = tid & 63;
    const int m31  = lane & 31;
    const int hi   = lane >> 5;
    const int bh   = blockIdx.x;
    const int qt   = blockIdx.y;
    const int b = bh >> 4, h = bh & 15;
    const _Float16* Qp = Qg + (size_t)bh * NT * ND;
    const _Float16* Kp = Kg + (size_t)bh * NT * ND;
    const _Float16* Vp = Vg + (size_t)bh * NT * ND;

    const int qrow_g = qt*256 + wid*32 + m31;

    half8 qfr[4];
    #pragma unroll
    for (int c = 0; c < 4; ++c)
        qfr[c] = *(const half8*)(Qp + (size_t)qrow_g*ND + 16*c + 8*hi);

    f32x16 o0, o1;
    #pragma unroll
    for (int e = 0; e < 16; ++e) { o0[e] = 0.f; o1[e] = 0.f; }
    float m_i = 8.0f, l_i = 0.0f;    // static bound; exact slow path guards it

    // staging geometry (512 threads)
    const int sr  = tid >> 3;            // K: key row 0..63
    const int sc0 = (tid & 7) * 8;       // K: d col base
    const int dp  = tid & 31;            // V: dword index (d = 2dp, 2dp+1)
    const int wv  = tid >> 5;            // V: key group 0..15 (4 keys each)
    const _Float16* kbase = Kp + (size_t)sr*ND + sc0;
    const _Float16* vbase = Vp + (size_t)(wv*4)*ND + 2*dp;

    half8 kv;
    unsigned int vr[4];

    #define LOADREGS(off)  do {                                              \
        kv = *(const half8*)(kbase + (size_t)(off)*ND);                      \
        _Pragma("unroll")                                                    \
        for (int j = 0; j < 4; ++j)                                          \
            vr[j] = *(const unsigned int*)(vbase + (size_t)((off) + j)*ND);  \
    } while (0)

    #define STOREBUF(bf)  do {                                               \
        *(half8*)&Ks[bf][sr][sc0] = kv;                                      \
        uint2v lod, hid;                                                     \
        lod[0] = __builtin_amdgcn_perm(vr[1], vr[0], 0x05040100u);           \
        lod[1] = __builtin_amdgcn_perm(vr[3], vr[2], 0x05040100u);           \
        hid[0] = __builtin_amdgcn_perm(vr[1], vr[0], 0x07060302u);           \
        hid[1] = __builtin_amdgcn_perm(vr[3], vr[2], 0x07060302u);           \
        *(uint2v*)&VsT[bf][2*dp][wv*4]     = lod;                            \
        *(uint2v*)&VsT[bf][2*dp + 1][wv*4] = hid;                            \
    } while (0)

    LOADREGS(0);
    STOREBUF(0);
    LOADREGS(64);

    for (int t = 0; t < 32; ++t) {
        const int cur = t & 1;
        __syncthreads();
        if (t < 31) STOREBUF(cur ^ 1);          // regs hold tile t+1
        if (t < 30) LOADREGS((t + 2) * 64);     // prefetch tile t+2

        // ---- S' = K.Q^T - m  (C initialized to -m_i) ----
        f32x16 st0, st1;
        const float mneg = -m_i;
        #pragma unroll
        for (int e = 0; e < 16; ++e) { st0[e] = mneg; st1[e] = mneg; }

        __builtin_amdgcn_s_setprio(1);
        #pragma unroll
        for (int c = 0; c < 4; ++c) {
            half8 kf0 = *(const half8*)&Ks[cur][m31][16*c + 8*hi];
            half8 kf1 = *(const half8*)&Ks[cur][32 + m31][16*c + 8*hi];
            st0 = MFMA32(kf0, qfr[c], st0);
            st1 = MFMA32(kf1, qfr[c], st1);
        }
        __builtin_amdgcn_s_setprio(0);

        // ---- p = exp2(s'), pack, fdot2 sums, fused p-max ----
        const fp16x2 ones2 = {(__fp16)1.0f, (__fp16)1.0f};
        unsigned int pku0[8], pku1[8];
        float rsA = 0.f, rsB = 0.f;
        float pmax = 0.f;
        #pragma unroll
        for (int j = 0; j < 8; ++j) {
            const float pa0 = fast_exp2(st0[2*j]);
            const float pa1 = fast_exp2(st0[2*j + 1]);
            const float pb0 = fast_exp2(st1[2*j]);
            const float pb1 = fast_exp2(st1[2*j + 1]);
            const fp16x2 h2a = __builtin_amdgcn_cvt_pkrtz(pa0, pa1);
            const fp16x2 h2b = __builtin_amdgcn_cvt_pkrtz(pb0, pb1);
            pku0[j] = __builtin_bit_cast(unsigned int, h2a);
            pku1[j] = __builtin_bit_cast(unsigned int, h2b);
            rsA = __builtin_amdgcn_fdot2(h2a, ones2, rsA, false);
            rsB = __builtin_amdgcn_fdot2(h2b, ones2, rsB, false);
            pmax = max3f(pmax, pa0, pa1);
            pmax = max3f(pmax, pb0, pb1);
        }
        float rs = rsA + rsB;
        rs += __shfl_xor(rs, 32);

        // ---- slow path: running bound exceeded (rare; exact rescale) ----
        if (__any(pmax > 1.0f)) {
            pmax = fmaxf(pmax, __shfl_xor(pmax, 32));
            const bool  grow  = pmax > 1.0f;
            const float delta = grow ? log2f(pmax) : 0.0f;
            const float alpha = grow ? __builtin_amdgcn_rcpf(pmax) : 1.0f;
            m_i += delta;
            l_i *= alpha;
            rs  *= alpha;
            fp16x2 am; am[0] = (__fp16)alpha; am[1] = (__fp16)alpha;
            #pragma unroll
            for (int j = 0; j < 8; ++j) {
                fp16x2 p0v = __builtin_bit_cast(fp16x2, pku0[j]) * am;
                fp16x2 p1v = __builtin_bit_cast(fp16x2, pku1[j]) * am;
                pku0[j] = __builtin_bit_cast(unsigned int, p0v);
                pku1[j] = __builtin_bit_cast(unsigned int, p1v);
            }
            #pragma unroll
            for (int reg = 0; reg < 16; ++reg) {
                const int qr = (reg & 3) + 8*(reg >> 2) + 4*hi;
                const float a = __shfl(alpha, qr);
                o0[reg] *= a; o1[reg] *= a;
            }
        }
        l_i += rs;

        // ---- O += P . V : permlane32_swap assembles the A-frag ----
        __builtin_amdgcn_s_setprio(1);
        #pragma unroll
        for (int kc = 0; kc < 4; ++kc) {
            const unsigned int a0 = (kc < 2) ? pku0[4*(kc & 1) + 0] : pku1[4*(kc & 1) + 0];
            const unsigned int a1 = (kc < 2) ? pku0[4*(kc & 1) + 1] : pku1[4*(kc & 1) + 1];
            const unsigned int b0 = (kc < 2) ? pku0[4*(kc & 1) + 2] : pku1[4*(kc & 1) + 2];
            const unsigned int b1 = (kc < 2) ? pku0[4*(kc & 1) + 3] : pku1[4*(kc & 1) + 3];
            uint2v rpa = __builtin_amdgcn_permlane32_swap(a0, b0, false, false);
            uint2v rpb = __builtin_amdgcn_permlane32_swap(a1, b1, false, false);
            uint4v u;
            u[0] = rpa[0]; u[1] = rpb[0]; u[2] = rpa[1]; u[3] = rpb[1];
            const half8 pa = __builtin_bit_cast(half8, u);
            const half8 vb0 = *(const half8*)&VsT[cur][m31][16*kc + 8*hi];
            const half8 vb1 = *(const half8*)&VsT[cur][32 + m31][16*kc + 8*hi];
            o0 = MFMA32(pa, vb0, o0);
            o1 = MFMA32(pa, vb1, o1);
        }
        __builtin_amdgcn_s_setprio(0);
    }

    // ---- epilogue: normalize (l redistributed to o-row layout), write ----
    #pragma unroll
    for (int reg = 0; reg < 16; ++reg) {
        const int qr = (reg & 3) + 8*(reg >> 2) + 4*hi;
        const float lq  = __shfl(l_i, qr);
        const float inv = 1.0f / lq;
        const int qg = qt*256 + wid*32 + qr;
        _Float16* dstp = Og + ((size_t)b*NT + qg)*NE + h*ND;
        dstp[m31]      = (_Float16)(o0[reg] * inv);
        dstp[32 + m31] = (_Float16)(o1[reg] * inv);
    }
    #undef LOADREGS
    #undef STOREBUF
}

// ============================================================================
// Kernel 3: fp16 MFMA out-projection: out(f32) = Oh * Woh^T + bias.
// ============================================================================
__global__ __launch_bounds__(256)
void out_proj_mfma_kernel(const _Float16* __restrict__ Ah,
                          const _Float16* __restrict__ Bh,
                          const float* __restrict__ bias,
                          float* __restrict__ out)
{
    __shared__ _Float16 Ash[128*32];
    __shared__ _Float16 Bsh[128*32];

    const int tid = threadIdx.x;
    const int wid = tid >> 6, lane = tid & 63;
    const int ln = lane & 15, g = lane >> 4;
    const int wrow = wid >> 1, wcol = wid & 1;
    const int m0 = blockIdx.x * 128, n0 = blockIdx.y * 128;

    const int r0 = tid >> 2, s0 = tid & 3;
    const int k8 = s0 ^ ((r0 >> 1) & 3);
    const _Float16* gA0 = Ah + (size_t)(m0 + r0)      * NE + k8*8;
    const _Float16* gA1 = Ah + (size_t)(m0 + r0 + 64) * NE + k8*8;
    const _Float16* gB0 = Bh + (size_t)(n0 + r0)      * NE + k8*8;
    const _Float16* gB1 = Bh + (size_t)(n0 + r0 + 64) * NE + k8*8;
    const int xr = g ^ ((ln >> 1) & 3);

    f32x4 acc[4][4];
    #pragma unroll
    for (int i = 0; i < 4; ++i)
        #pragma unroll
        for (int j = 0; j < 4; ++j) acc[i][j] = (f32x4){0.f,0.f,0.f,0.f};

    half8 va0 = *(const half8*)gA0;
    half8 va1 = *(const half8*)gA1;
    half8 vb0 = *(const half8*)gB0;
    half8 vb1 = *(const half8*)gB1;

    for (int kt = 0; kt < NE; kt += 32) {
        if (kt) __syncthreads();
        *(half8*)&Ash[tid*8]       = va0;
        *(half8*)&Ash[(tid+256)*8] = va1;
        *(half8*)&Bsh[tid*8]       = vb0;
        *(half8*)&Bsh[(tid+256)*8] = vb1;
        __syncthreads();
        const int kn = kt + 32;
        if (kn < NE) {
            va0 = *(const half8*)(gA0 + kn);
            va1 = *(const half8*)(gA1 + kn);
            vb0 = *(const half8*)(gB0 + kn);
            vb1 = *(const half8*)(gB1 + kn);
        }
        half8 af[4], bf[4];
        #pragma unroll
        for (int mf = 0; mf < 4; ++mf)
            af[mf] = *(const half8*)&Ash[(wrow*64 + mf*16 + ln)*32 + xr*8];
        #pragma unroll
        for (int nf = 0; nf < 4; ++nf)
            bf[nf] = *(const half8*)&Bsh[(wcol*64 + nf*16 + ln)*32 + xr*8];
        __builtin_amdgcn_s_setprio(1);
        #pragma unroll
        for (int mf = 0; mf < 4; ++mf)
            #pragma unroll
            for (int nf = 0; nf < 4; ++nf)
                acc[mf][nf] = MFMA16(af[mf], bf[nf], acc[mf][nf]);
        __builtin_amdgcn_s_setprio(0);
    }

    float cb[4];
    #pragma unroll
    for (int nf = 0; nf < 4; ++nf) cb[nf] = bias[n0 + wcol*64 + nf*16 + ln];

    #pragma unroll
    for (int mf = 0; mf < 4; ++mf)
        #pragma unroll
        for (int r = 0; r < 4; ++r) {
            const int m = m0 + wrow*64 + mf*16 + g*4 + r;
            #pragma unroll
            for (int nf = 0; nf < 4; ++nf)
                out[(size_t)m*NE + n0 + wcol*64 + nf*16 + ln] = acc[mf][nf][r] + cb[nf];
        }
}

extern "C" void kernel_launch(void* const* d_in, const int* in_sizes, int n_in,
                              void* d_out, int out_size, void* d_ws, size_t ws_size,
                              hipStream_t stream)
{
    const float* X   = (const float*)d_in[0];
    const float* pos = (const float*)d_in[1];
    const float* Wi  = (const float*)d_in[2];
    const float* bi  = (const float*)d_in[3];
    const float* Wo  = (const float*)d_in[4];
    const float* bo  = (const float*)d_in[5];
    const float* fr  = (const float*)d_in[6];
    float* out = (float*)d_out;

    _Float16* Xh  = (_Float16*)d_ws;            // 8388608
    _Float16* Wih = Xh  + 8388608;              // 3145728
    _Float16* Woh = Wih + 3145728;              // 1048576
    _Float16* Qh  = Woh + 1048576;              // 8388608
    _Float16* Kh  = Qh  + 8388608;
    _Float16* Vh  = Kh  + 8388608;
    _Float16* Oh  = Vh  + 8388608;

    cvt_kernel          <<<3072, 256, 0, stream>>>(X, Wi, Wo, Xh, Wih, Woh);
    qkv_mfma_kernel     <<<dim3(64, 24), 256, 0, stream>>>(Xh, Wih, bi, pos, fr, Qh, Kh, Vh);
    attn_mfma_kernel    <<<dim3(64, 8), 512, 0, stream>>>(Qh, Kh, Vh, Oh);
    out_proj_mfma_kernel<<<dim3(64, 8),  256, 0, stream>>>(Oh, Woh, bo, out);
}